// Round 13
// baseline (450.669 us; speedup 1.0000x reference)
//
#include <hip/hip_runtime.h>
#include <hip/hip_bf16.h>
#include <math.h>

#define NB 4
#define NN 1500
#define KNB 30
#define H 128
#define NHEADS 4
#define FFH 512
#define NODE_FEAT 1024
#define NROWS (NB*NN)
#define LN_EPS 1e-6f

// P layout per node: 1536 B = [Q f32 x128 | (bytes 1280..1535) Q'' bf16 x128];
// attn overwrites bf16 cols 0..639 with U = [Ebar(h*128+e) x512 | vpart x128].
#define P_F32_STRIDE 384
#define P_BF16_STRIDE 768

// Wn_t per-layer: 528 rows x 128 k (bf16). rows 0-127 Q, 128-255 Q'' (WQ2),
// 256-259 wqg, 260-271 zero pad, 272-399 Kbot, 400-527 Vbot.
#define WNT_STRIDE 67584

typedef __attribute__((ext_vector_type(8))) short s8v;   // 8 bf16 = 4 VGPRs (MFMA A/B frag)
typedef __attribute__((ext_vector_type(4))) float f4v;   // MFMA C/D frag

__device__ __forceinline__ float bf_lo(unsigned u){ union{unsigned i; float f;} v; v.i = u<<16; return v.f; }
__device__ __forceinline__ float bf_hi(unsigned u){ union{unsigned i; float f;} v; v.i = u & 0xffff0000u; return v.f; }

// ---------------------------------------------------------------- topk (radix select)
__device__ __forceinline__ void find_bucket30(
    const unsigned* hist, int base0, int t, int lane, int wave,
    int* wsum, int* res)
{
    int h[16], s = 0;
    const uint4* hp = (const uint4*)&hist[(t & 127) * 16];
    int sh = (t >> 7) << 4;
    uint4 w[4] = {hp[0], hp[1], hp[2], hp[3]};
#pragma unroll
    for (int i = 0; i < 4; i++) {
        h[i*4+0] = (w[i].x >> sh) & 0xffff;
        h[i*4+1] = (w[i].y >> sh) & 0xffff;
        h[i*4+2] = (w[i].z >> sh) & 0xffff;
        h[i*4+3] = (w[i].w >> sh) & 0xffff;
        s += h[i*4+0] + h[i*4+1] + h[i*4+2] + h[i*4+3];
    }
    int inc = s;
#pragma unroll
    for (int off = 1; off < 64; off <<= 1) {
        int o = __shfl_up(inc, off, 64);
        if (lane >= off) inc += o;
    }
    if (lane == 63) wsum[wave] = inc;
    __syncthreads();
    int base = base0 + inc - s;
    for (int w2 = 0; w2 < wave; w2++) base += wsum[w2];
    if (base < KNB && base + s >= KNB) {
        int running = base;
#pragma unroll
        for (int i = 0; i < 16; i++) {
            if (running < KNB && running + h[i] >= KNB) { res[0] = (t<<4)|i; res[1] = running; break; }
            running += h[i];
        }
    }
    __syncthreads();
}

__global__ __launch_bounds__(256) void topk_kernel(
    const float* __restrict__ X, const float* __restrict__ mask,
    int* __restrict__ E_idx, float* __restrict__ D_nb)
{
    int row = blockIdx.x;            // b*NN + i
    int b = row / NN;
    int t = threadIdx.x;
    int wave = t >> 6, lane = t & 63;
    __shared__ float d_adj[NN];
    __shared__ unsigned hist[2048];
    __shared__ float redw[4];
    __shared__ int   wsum[4];
    __shared__ int   res[2];
    __shared__ int   cand[64];
    __shared__ int   ncand;

    float xi0 = X[row*3+0], xi1 = X[row*3+1], xi2 = X[row*3+2];
    float mi = mask[row];

    float dr[6], m2r[6];
    float lmax = -1e30f;
#pragma unroll
    for (int q = 0; q < 6; q++) {
        int j = t + q*256;
        float d = 0.f, m2 = 0.f;
        if (j < NN) {
            float dx = xi0 - X[(b*NN+j)*3+0];
            float dy = xi1 - X[(b*NN+j)*3+1];
            float dz = xi2 - X[(b*NN+j)*3+2];
            d  = sqrtf(dx*dx + dy*dy + dz*dz + 1e-6f);
            m2 = mi * mask[b*NN+j];
            lmax = fmaxf(lmax, m2*d);
        }
        dr[q] = d; m2r[q] = m2;
    }
    for (int q = t; q < 2048; q += 256) hist[q] = 0;
#pragma unroll
    for (int off = 32; off > 0; off >>= 1)
        lmax = fmaxf(lmax, __shfl_xor(lmax, off, 64));
    if (lane == 0) redw[wave] = lmax;
    if (t == 0) ncand = 0;
    __syncthreads();
    float rowmax = fmaxf(fmaxf(redw[0], redw[1]), fmaxf(redw[2], redw[3]));

    unsigned kreg[6];
#pragma unroll
    for (int q = 0; q < 6; q++) {
        int j = t + q*256;
        if (j < NN) {
            float dv = m2r[q]*dr[q] + (1.0f - m2r[q])*rowmax;   // >= 0
            d_adj[j] = dv;
            unsigned key = __float_as_uint(dv);
            kreg[q] = key;
            unsigned bkt = key >> 20;
            atomicAdd(&hist[bkt & 2047], 1u << ((bkt >> 11) << 4));
        } else kreg[q] = 0xFFFFFFFFu;
    }
    __syncthreads();

    find_bucket30(hist, 0, t, lane, wave, wsum, res);
    int B1 = res[0], nb1 = res[1];

    for (int q = t; q < 2048; q += 256) hist[q] = 0;
    __syncthreads();
#pragma unroll
    for (int q = 0; q < 6; q++) {
        if ((kreg[q] >> 20) == (unsigned)B1) {
            unsigned bkt = (kreg[q] >> 8) & 0xFFF;
            atomicAdd(&hist[bkt & 2047], 1u << ((bkt >> 11) << 4));
        }
    }
    __syncthreads();

    find_bucket30(hist, nb1, t, lane, wave, wsum, res);
    unsigned Bfull = ((unsigned)B1 << 12) | (unsigned)res[0];

#pragma unroll
    for (int q = 0; q < 6; q++) {
        if ((kreg[q] >> 8) <= Bfull) {
            int slot = atomicAdd(&ncand, 1);
            if (slot < 64) cand[slot] = t + q*256;
        }
    }
    __syncthreads();

    if (wave == 0) {
        int nc = min(ncand, 64);
        if (lane < nc) {
            int j = cand[lane];
            float v = d_adj[j];
            int rank = 0;
            for (int m = 0; m < nc; m++) {
                int jm = cand[m];
                float vm = d_adj[jm];
                rank += (vm < v || (vm == v && jm < j)) ? 1 : 0;
            }
            if (rank < KNB) {
                E_idx[row*KNB + rank] = j;
                D_nb[row*KNB + rank]  = v;
            }
        }
    }
}

// ---------------------------------------------------------------- W_edge transpose+cast: W_edge_t[n][k] bf16 (128x32)
__global__ __launch_bounds__(256) void wprep_edge_kernel(
    const float* __restrict__ W_edge, __hip_bfloat16* __restrict__ W_edge_t)
{
    int tid = blockIdx.x*256 + threadIdx.x;  // 4096
    int n = tid >> 5, k = tid & 31;
    W_edge_t[tid] = __float2bfloat16(W_edge[k*H + n]);
}

// ---------------------------------------------------------------- edge features -> E_ln (bf16) + per-edge (rs, mu*rs), MFMA
__global__ __launch_bounds__(256) void edge_kernel(
    const int* __restrict__ E_idx, const float* __restrict__ D_nb,
    const __hip_bfloat16* __restrict__ W_edge_t, const float* __restrict__ ln_g,
    const float* __restrict__ ln_b, __hip_bfloat16* __restrict__ E_ln,
    float* __restrict__ EMS)
{
    int g0 = blockIdx.x * 2;
    int t = threadIdx.x;
    int wave = t >> 6, lane = t & 63, lm = lane & 15, lq = lane >> 4;
    __shared__ __hip_bfloat16 Es[64*136];

    int row = wave*16 + lm;
    int rr = row < 60 ? row : 59;
    int node = g0 + (rr >= KNB ? 1 : 0);
    int e = node*KNB + (rr >= KNB ? rr - KNB : rr);
    float drel = (float)(E_idx[e] - (node % NN));
    float dnb  = D_nb[e];

    const float FR[8] = {1.f, 0.31622776601683794f, 0.1f, 0.031622776601683794f,
                         0.01f, 0.0031622776601683794f, 0.001f, 0.00031622776601683794f};
    union { s8v v; __hip_bfloat16 h[8]; } af;
    if (lq == 0) {
#pragma unroll
        for (int j = 0; j < 8; j++) af.h[j] = __float2bfloat16(cosf(drel*FR[j]));
    } else if (lq == 1) {
#pragma unroll
        for (int j = 0; j < 8; j++) af.h[j] = __float2bfloat16(sinf(drel*FR[j]));
    } else {
        int f0 = (lq-2)*8;
#pragma unroll
        for (int j = 0; j < 8; j++) {
            float mu = (20.0f/15.0f) * (float)(f0+j);
            float z = (dnb - mu) * 0.8f;
            af.h[j] = __float2bfloat16(expf(-z*z));
        }
    }

    f4v acc[8];
#pragma unroll
    for (int nt = 0; nt < 8; nt++) {
        s8v bf = *(const s8v*)&W_edge_t[(nt*16+lm)*32 + lq*8];
        f4v z = {0.f,0.f,0.f,0.f};
        acc[nt] = __builtin_amdgcn_mfma_f32_16x16x32_bf16(af.v, bf, z, 0,0,0);
    }

    float gv[8], bv[8];
#pragma unroll
    for (int nt = 0; nt < 8; nt++) { gv[nt] = ln_g[nt*16+lm]; bv[nt] = ln_b[nt*16+lm]; }
#pragma unroll
    for (int r = 0; r < 4; r++) {
        float sm = 0.f, sq = 0.f;
#pragma unroll
        for (int nt = 0; nt < 8; nt++) { float x = acc[nt][r]; sm += x; sq += x*x; }
#pragma unroll
        for (int m = 1; m < 16; m <<= 1) {
            sm += __shfl_xor(sm, m, 64);
            sq += __shfl_xor(sq, m, 64);
        }
        float mu = sm * (1.0f/H);
        float rs = rsqrtf(sq*(1.0f/H) - mu*mu + LN_EPS);
        int erow = wave*16 + lq*4 + r;
        if (lm == 0 && erow < 60) {
            EMS[(g0*KNB + erow)*2]     = rs;
            EMS[(g0*KNB + erow)*2 + 1] = mu*rs;
        }
#pragma unroll
        for (int nt = 0; nt < 8; nt++)
            Es[erow*136 + nt*16 + lm] =
                __float2bfloat16(gv[nt]*(acc[nt][r]-mu)*rs + bv[nt]);
    }
    __syncthreads();

    __hip_bfloat16* dst = E_ln + (size_t)g0*KNB*H;
    for (int q = t; q < 960; q += 256) {
        int r = q >> 4, c8 = (q & 15) * 8;
        *(s8v*)&dst[r*H + c8] = *(const s8v*)&Es[r*136 + c8];
    }
}

// ---------------------------------------------------------------- W_v transpose+cast: Wv_t[n][k] bf16
__global__ __launch_bounds__(256) void wprep_v_kernel(
    const float* __restrict__ W_v, __hip_bfloat16* __restrict__ Wv_t)
{
    int tid = blockIdx.x*256 + threadIdx.x;  // 131072
    int n = tid & 127, k = tid >> 7;
    Wv_t[(size_t)n*NODE_FEAT + k] = __float2bfloat16(W_v[k*H + n]);
}

// ---------------------------------------------------------------- fold W_e into per-layer edge K/V (fp32, [l][col][e])
__global__ __launch_bounds__(128) void wprep_kv_kernel(
    const float* __restrict__ W_e, const float* __restrict__ b_e,
    const float* __restrict__ Wk, const float* __restrict__ Wv,
    float* __restrict__ Wkv_f, float* __restrict__ bias_kv)
{
    int l = blockIdx.x >> 8;
    int n = blockIdx.x & 255;
    int t = threadIdx.x;             // t = e (0..127)
    int col = n & 127;
    const float* W = (n < 128) ? (Wk + l*2*H*H) : (Wv + l*2*H*H);
    __shared__ float wcol[128];
    wcol[t] = W[t*H + col];          // rows 0..127 = h_E block
    __syncthreads();
    float a = 0.f;
    for (int c = 0; c < H; c += 4) {
        float4 we = *(const float4*)&W_e[t*H + c];
        a += we.x*wcol[c] + we.y*wcol[c+1] + we.z*wcol[c+2] + we.w*wcol[c+3];
    }
    Wkv_f[(size_t)(l*256 + n)*H + t] = a;   // Wek/Wev [e=t][col=n], stored [n][e]
    if (t == 0) {
        float bsum = 0.f;
        for (int c = 0; c < H; c++) bsum += b_e[c]*wcol[c];
        bias_kv[l*256 + n] = bsum;
    }
}

// ---------------------------------------------------------------- rank-32 fold part 1:
// M[l][n][f] = sum_e Wek[e][n]*g[e]*W_edge[f][e];  vg[l][n] = sum_e Wek[e][n]*g[e]
__global__ __launch_bounds__(128) void wprep_m_kernel(
    const float* __restrict__ Wkv_f, const float* __restrict__ W_edge,
    const float* __restrict__ ln_e_g,
    float* __restrict__ M_buf, float* __restrict__ vg_buf)
{
    int l = blockIdx.x >> 7;
    int n = blockIdx.x & 127;
    int t = threadIdx.x;
    __shared__ float wg_s[128];
    wg_s[t] = Wkv_f[(size_t)(l*256 + n)*H + t] * ln_e_g[t];
    __syncthreads();
    if (t < 32) {
        float a = 0.f;
        for (int e = 0; e < 128; e++) a += wg_s[e] * W_edge[t*H + e];
        M_buf[((size_t)(l*128 + n))*32 + t] = a;
    } else if (t == 32) {
        float a = 0.f;
        for (int e = 0; e < 128; e++) a += wg_s[e];
        vg_buf[l*128 + n] = a;
    }
}

// ---------------------------------------------------------------- rank-32 fold part 2:
// WQ2[l][c][h*32+f] = sum_d Wq[c][h32+d]*M[h32+d][f] -> Wn_t rows 128..255
// wqg[l][c][h]     = sum_d Wq[c][h32+d]*vg[h32+d]    -> Wn_t rows 256..259; 260..271 zero
__global__ __launch_bounds__(128) void wprep_q2_kernel(
    const float* __restrict__ Wq, const float* __restrict__ M_buf,
    const float* __restrict__ vg_buf, __hip_bfloat16* __restrict__ Wn_t)
{
    int l = blockIdx.x >> 7;
    int c = blockIdx.x & 127;
    int t = threadIdx.x;            // h*32+f
    int h = t >> 5, f = t & 31;
    __shared__ float wq_s[128];
    wq_s[t] = Wq[(size_t)l*16384 + c*128 + t];
    __syncthreads();
    float a = 0.f;
#pragma unroll
    for (int d = 0; d < 32; d++)
        a += wq_s[h*32 + d] * M_buf[((size_t)(l*128 + h*32 + d))*32 + f];
    Wn_t[(size_t)l*WNT_STRIDE + (128 + t)*H + c] = __float2bfloat16(a);
    if (t < 4) {
        float b = 0.f;
        for (int d = 0; d < 32; d++)
            b += wq_s[t*32 + d] * vg_buf[l*128 + t*32 + d];
        Wn_t[(size_t)l*WNT_STRIDE + (256 + t)*H + c] = __float2bfloat16(b);
    }
    if (t < 12) Wn_t[(size_t)l*WNT_STRIDE + (260 + t)*H + c] = __float2bfloat16(0.f);
}

// ---------------------------------------------------------------- WOP fold: WoU_t [l][n][k=640]
// k<512: sum_d Wev[e][h*32+d]*Wo[h*32+d][n];  k>=512: Wo[k-512][n]
__global__ __launch_bounds__(128) void wprep_op_kernel(
    const float* __restrict__ Wo, const float* __restrict__ Wkv_f,
    __hip_bfloat16* __restrict__ WoU_t)
{
    int l = blockIdx.x / 640;
    int kk = blockIdx.x - l*640;
    int n = threadIdx.x;
    __shared__ float wev[32];
    if (kk < 512) {
        int h = kk >> 7;
        int e = kk & 127;
        if (n < 32) wev[n] = Wkv_f[(size_t)(l*256 + 128 + h*32 + n)*H + e];
    }
    __syncthreads();
    float v;
    if (kk < 512) {
        int h = kk >> 7;
        float a = 0.f;
#pragma unroll
        for (int d = 0; d < 32; d++)
            a += wev[d]*Wo[(size_t)l*16384 + (h*32+d)*128 + n];
        v = a;
    } else {
        v = Wo[(size_t)l*16384 + (kk-512)*128 + n];
    }
    WoU_t[((size_t)l*128 + n)*640 + kk] = __float2bfloat16(v);
}

// ---------------------------------------------------------------- transpose+cast FF weights + Wn_t Q/Kbot/Vbot parts
__global__ __launch_bounds__(256) void wprep_post_kernel(
    const float* __restrict__ Wf1, const float* __restrict__ Wf2,
    const float* __restrict__ Wq, const float* __restrict__ Wk,
    const float* __restrict__ Wv,
    __hip_bfloat16* __restrict__ Wf1_t, __hip_bfloat16* __restrict__ Wf2_t,
    __hip_bfloat16* __restrict__ Wn_t)
{
    int id = blockIdx.x*256 + threadIdx.x;   // < 720896
    int l = id / 180224;
    int r = id - l*180224;
    float v; __hip_bfloat16* dst;
    if (r < 65536) {
        int n = r >> 7, k = r & 127;
        v = Wf1[(size_t)l*65536 + k*512 + n];
        dst = Wf1_t + (size_t)l*65536 + r;
    } else if (r < 131072) {
        int rr = r - 65536;
        int n = rr >> 9, k = rr & 511;
        v = Wf2[(size_t)l*65536 + k*128 + n];
        dst = Wf2_t + (size_t)l*65536 + rr;
    } else if (r < 147456) {
        int rr = r - 131072;                  // Q block: rows 0..127
        int n = rr >> 7, k = rr & 127;
        v = Wq[(size_t)l*16384 + k*128 + n];
        dst = Wn_t + (size_t)l*WNT_STRIDE + rr;
    } else {
        int rr = r - 147456;                  // Kbot/Vbot: n_local 0..255 -> rows 272..527
        int n = rr >> 7, k = rr & 127;
        v = (n < 128) ? Wk[(size_t)l*32768 + (128+k)*128 + n]
                      : Wv[(size_t)l*32768 + (128+k)*128 + (n-128)];
        dst = Wn_t + (size_t)l*WNT_STRIDE + 272*H + rr;
    }
    *dst = __float2bfloat16(v);
}

// ---------------------------------------------------------------- h_V = V @ W_v + b_v  (MFMA)
// + fused layer-0 node projections (33 tiles: Q | Q'' | qg | Kbot | Vbot)
__global__ __launch_bounds__(512) void hv_init_kernel(
    const float* __restrict__ V, const __hip_bfloat16* __restrict__ Wv_t,
    const float* __restrict__ b_v, float* __restrict__ hv,
    const __hip_bfloat16* __restrict__ Wn_t, float* __restrict__ P,
    __hip_bfloat16* __restrict__ PKV, float* __restrict__ qg_buf)
{
    int row0 = blockIdx.x * 32;
    int t = threadIdx.x;
    int wave = t >> 6, lane = t & 63, lm = lane & 15, lq = lane >> 4;
    __shared__ __hip_bfloat16 Vs[32*1032];   // pitch 1032 (2-way bank alias only)
    __shared__ __hip_bfloat16 zs[32*136];

    for (int q = t; q < 8192; q += 512) {
        int r = q >> 8, c4 = (q & 255) * 4;
        int gr = row0 + r; if (gr > NROWS-1) gr = NROWS-1;
        float4 v4 = *(const float4*)&V[(size_t)gr*NODE_FEAT + c4];
        union { ushort u[4]; uint2 w; } pk;
        pk.u[0] = __bfloat16_as_ushort(__float2bfloat16(v4.x));
        pk.u[1] = __bfloat16_as_ushort(__float2bfloat16(v4.y));
        pk.u[2] = __bfloat16_as_ushort(__float2bfloat16(v4.z));
        pk.u[3] = __bfloat16_as_ushort(__float2bfloat16(v4.w));
        *(uint2*)&Vs[r*1032 + c4] = pk.w;
    }
    __syncthreads();

    // h_V GEMM: wave w -> n-tile w; weight frag reused across m-tiles 0/1
    {
        int cc = wave*16 + lm;
        float b = b_v[cc];
        f4v a0 = {0.f,0.f,0.f,0.f}, a1 = a0;
        for (int ks = 0; ks < 32; ks++) {
            s8v wf = *(const s8v*)&Wv_t[(size_t)(wave*16+lm)*NODE_FEAT + ks*32 + lq*8];
            s8v f0 = *(const s8v*)&Vs[lm*1032 + ks*32 + lq*8];
            s8v f1 = *(const s8v*)&Vs[(16+lm)*1032 + ks*32 + lq*8];
            a0 = __builtin_amdgcn_mfma_f32_16x16x32_bf16(f0, wf, a0, 0,0,0);
            a1 = __builtin_amdgcn_mfma_f32_16x16x32_bf16(f1, wf, a1, 0,0,0);
        }
#pragma unroll
        for (int r = 0; r < 4; r++) {
            int rr0 = lq*4 + r, rr1 = 16 + lq*4 + r;
            int g0 = row0 + rr0, g1 = row0 + rr1;
            float v0 = a0[r] + b, v1 = a1[r] + b;
            if (g0 < NROWS) hv[(size_t)g0*H + cc] = v0;
            if (g1 < NROWS) hv[(size_t)g1*H + cc] = v1;
            zs[rr0*136+cc] = __float2bfloat16(v0);
            zs[rr1*136+cc] = __float2bfloat16(v1);
        }
    }
    __syncthreads();

    // layer-0 node projections: 33 tiles over 8 waves (5 each, guard)
    __hip_bfloat16* Pb = (__hip_bfloat16*)P;
    for (int ntl = 0; ntl < 5; ntl++) {
        int nt = wave*5 + ntl;
        if (nt >= 33) break;
        int cc = nt*16 + lm;
        f4v a0 = {0.f,0.f,0.f,0.f}, a1 = a0;
#pragma unroll
        for (int ks = 0; ks < 4; ks++) {
            s8v wf = *(const s8v*)&Wn_t[(size_t)(nt*16+lm)*H + ks*32 + lq*8];
            s8v f0 = *(const s8v*)&zs[lm*136 + ks*32 + lq*8];
            s8v f1 = *(const s8v*)&zs[(16+lm)*136 + ks*32 + lq*8];
            a0 = __builtin_amdgcn_mfma_f32_16x16x32_bf16(f0, wf, a0, 0,0,0);
            a1 = __builtin_amdgcn_mfma_f32_16x16x32_bf16(f1, wf, a1, 0,0,0);
        }
#pragma unroll
        for (int mt = 0; mt < 2; mt++) {
            f4v* ap = mt ? &a1 : &a0;
#pragma unroll
            for (int r = 0; r < 4; r++) {
                int rr = row0 + mt*16 + lq*4 + r;
                if (rr < NROWS) {
                    float av = (*ap)[r];
                    if (cc < 128)
                        P[(size_t)rr*P_F32_STRIDE + cc] = av;
                    else if (cc < 256)
                        Pb[(size_t)rr*P_BF16_STRIDE + 640 + (cc-128)] = __float2bfloat16(av);
                    else if (cc < 272) {
                        if (cc < 260) qg_buf[rr*4 + (cc-256)] = av;
                    } else
                        PKV[(size_t)rr*256 + (cc-272)] = __float2bfloat16(av);
                }
            }
        }
    }
}

// ---------------------------------------------------------------- attention: 2 nodes/block, 5-phase (proven shape).
// Rank-32 logits: logit_edge = rs*(Q''.Phi) - mu*rs*qg  (qb const-over-k cancels
// in softmax). Phi recomputed in-block from E_idx/D_nb; E_ln staged only for Ebar.
__global__ __launch_bounds__(256) void attn_kernel(
    const __hip_bfloat16* __restrict__ E_ln, const float* __restrict__ biasv,
    float* __restrict__ P, const __hip_bfloat16* __restrict__ PKV,
    const int* __restrict__ E_idx, const float* __restrict__ D_nb,
    const float* __restrict__ EMS, const float* __restrict__ qg_buf,
    const float* __restrict__ mask)
{
    int g0 = blockIdx.x * 2;
    int t = threadIdx.x;
    int wave = t >> 6, lane = t & 63, lm = lane & 15, lq = lane >> 4;
    __shared__ __hip_bfloat16 Es[60*136];    // E_ln rows (for Ebar), 16320 B
    __shared__ __hip_bfloat16 Ps[60*40];     // Phi rows (32 used), 4800 B
    __shared__ __hip_bfloat16 Qps[2*136];    // Q'' bf16 (128 used)
    __shared__ float Qs[2*128];              // Q f32
    __shared__ float att_s[2*128];           // [node][h*32+k]
    __shared__ float ssum[8];                // [node][h]
    __shared__ float mv_s[60];
    __shared__ float rs_s[60], murs_s[60];
    __shared__ float qgs[8];
    __shared__ int   nbr[60];

    const __hip_bfloat16* hebase = E_ln + (size_t)g0*KNB*H;
    for (int q = t; q < 960; q += 256) {
        int r = q >> 4, c8 = (q & 15) * 8;
        *(s8v*)&Es[r*136 + c8] = *(const s8v*)&hebase[r*H + c8];
    }
    const __hip_bfloat16* Pb = (const __hip_bfloat16*)P;
    if (t < 32) {
        int node = t >> 4, c8 = (t & 15)*8;
        *(s8v*)&Qps[node*136 + c8] = *(const s8v*)&Pb[(size_t)(g0+node)*P_BF16_STRIDE + 640 + c8];
    }
    {
        int node = t >> 7, c = t & 127;
        Qs[t] = P[(size_t)(g0+node)*P_F32_STRIDE + c];
    }
    if (t < 60) {
        int gn = g0 + t/30;
        int b = gn / NN;
        int idx = E_idx[gn*KNB + (t%30)];
        nbr[t]  = b*NN + idx;
        mv_s[t] = mask[gn] * mask[b*NN + idx];
        float2 em = ((const float2*)EMS)[g0*KNB + t];
        rs_s[t] = em.x; murs_s[t] = em.y;
    }
    if (t < 8) qgs[t] = qg_buf[(g0 + (t>>2))*4 + (t&3)];
    // Phi recompute: 4 threads per edge (seg = 8-dim slice)
    if (t < 240) {
        int r = t >> 2, seg = t & 3;
        int gn = g0 + r/30;
        int e = gn*KNB + (r%30);
        float drel = (float)(E_idx[e] - (gn % NN));
        float dnb  = D_nb[e];
        const float FR[8] = {1.f, 0.31622776601683794f, 0.1f, 0.031622776601683794f,
                             0.01f, 0.0031622776601683794f, 0.001f, 0.00031622776601683794f};
        union { s8v v; __hip_bfloat16 h[8]; } pf;
        if (seg == 0) {
#pragma unroll
            for (int j = 0; j < 8; j++) pf.h[j] = __float2bfloat16(cosf(drel*FR[j]));
        } else if (seg == 1) {
#pragma unroll
            for (int j = 0; j < 8; j++) pf.h[j] = __float2bfloat16(sinf(drel*FR[j]));
        } else {
            int f0 = (seg-2)*8;
#pragma unroll
            for (int j = 0; j < 8; j++) {
                float mu = (20.0f/15.0f) * (float)(f0+j);
                float z = (dnb - mu) * 0.8f;
                pf.h[j] = __float2bfloat16(expf(-z*z));
            }
        }
        *(s8v*)&Ps[r*40 + seg*8] = pf.v;
    }
    __syncthreads();

    // logits: rank-32 edge dot + Kbot gather dot
    if (t < 240) {
        int node = t/120, tt = t%120, h = tt/30, kk = tt%30;
        int r = node*30 + kk;
        const uint4* pp = (const uint4*)&Ps[r*40];
        const uint4* qp = (const uint4*)&Qps[node*136 + h*32];
        float a = 0.f;
#pragma unroll
        for (int j = 0; j < 4; j++) {
            uint4 e4 = pp[j], q4 = qp[j];
            a += bf_lo(e4.x)*bf_lo(q4.x) + bf_hi(e4.x)*bf_hi(q4.x);
            a += bf_lo(e4.y)*bf_lo(q4.y) + bf_hi(e4.y)*bf_hi(q4.y);
            a += bf_lo(e4.z)*bf_lo(q4.z) + bf_hi(e4.z)*bf_hi(q4.z);
            a += bf_lo(e4.w)*bf_lo(q4.w) + bf_hi(e4.w)*bf_hi(q4.w);
        }
        a = rs_s[r]*a - murs_s[r]*qgs[node*4 + h];
        const uint4* kb = (const uint4*)(PKV + (size_t)nbr[r]*256 + h*32);
        const float* q = &Qs[node*128 + h*32];
#pragma unroll
        for (int j = 0; j < 4; j++) {
            uint4 u = kb[j];
            const float* q8 = q + j*8;
            a += q8[0]*bf_lo(u.x) + q8[1]*bf_hi(u.x)
               + q8[2]*bf_lo(u.y) + q8[3]*bf_hi(u.y)
               + q8[4]*bf_lo(u.z) + q8[5]*bf_hi(u.z)
               + q8[6]*bf_lo(u.w) + q8[7]*bf_hi(u.w);
        }
        att_s[node*128 + h*32 + kk] =
            (mv_s[r] > 0.f) ? a*0.17677669529663687f : -3.4028235e38f;
    }
    __syncthreads();

    // parallel softmax: wave w = node w (w<2), 16 lanes per head, 2 entries/lane
    if (wave < 2) {
        int node = wave, h = lq, j = lm;
        float* ap = &att_s[node*128 + h*32];
        const float* mp = &mv_s[node*30];
        float a0 = ap[j];
        float a1 = (j+16 < KNB) ? ap[j+16] : -3.4028235e38f;
        float mx = fmaxf(a0, a1);
#pragma unroll
        for (int m = 1; m < 16; m <<= 1) mx = fmaxf(mx, __shfl_xor(mx, m, 64));
        float e0 = __expf(a0 - mx);
        float e1 = (j+16 < KNB) ? __expf(a1 - mx) : 0.f;
        float s = e0 + e1;
#pragma unroll
        for (int m = 1; m < 16; m <<= 1) s += __shfl_xor(s, m, 64);
        float inv = 1.0f / s;
        float w0 = e0 * inv * mp[j];
        float w1 = (j+16 < KNB) ? e1 * inv * mp[j+16] : 0.f;
        ap[j] = w0;
        if (j+16 < KNB) ap[j+16] = w1;
        float ss = w0 + w1;
#pragma unroll
        for (int m = 1; m < 16; m <<= 1) ss += __shfl_xor(ss, m, 64);
        if (j == 0) ssum[node*4 + h] = ss;
    }
    __syncthreads();

    // U = [Ebar(512) | vpart(128)] bf16, written in-place over P node region
    {
        int node = t >> 7, c = t & 127, h = c >> 5;
        __hip_bfloat16* Ub = (__hip_bfloat16*)P + (size_t)(g0+node)*P_BF16_STRIDE;
        const float* ap = &att_s[node*128];
        const int* nb = &nbr[node*30];

        float u = ssum[node*4 + h] * biasv[c];
        const float* ah = ap + h*32;
        for (int k = 0; k < KNB; k++)
            u += ah[k] * __bfloat162float(PKV[(size_t)nb[k]*256 + 128 + c]);
        Ub[512 + c] = __float2bfloat16(u);

        float s0 = 0.f, s1 = 0.f, s2 = 0.f, s3 = 0.f;
        for (int k = 0; k < KNB; k++) {
            float e = __bfloat162float(Es[(node*30+k)*136 + c]);
            s0 += ap[k]      * e;
            s1 += ap[32+k]   * e;
            s2 += ap[64+k]   * e;
            s3 += ap[96+k]   * e;
        }
        Ub[c]       = __float2bfloat16(s0);
        Ub[128 + c] = __float2bfloat16(s1);
        Ub[256 + c] = __float2bfloat16(s2);
        Ub[384 + c] = __float2bfloat16(s3);
    }
}

// ---------------------------------------------------------------- WoU(K=640) + LN1 + FF + LN2 (+ next-layer node proj | out), MFMA
__global__ __launch_bounds__(512) void post_kernel(
    float* __restrict__ hv, float* __restrict__ P,
    __hip_bfloat16* __restrict__ PKV, float* __restrict__ qg_buf,
    const float* __restrict__ mask,
    const __hip_bfloat16* __restrict__ WoU_t,
    const float* __restrict__ ln1g, const float* __restrict__ ln1b,
    const float* __restrict__ ln2g, const float* __restrict__ ln2b,
    const __hip_bfloat16* __restrict__ Wf1_t, const float* __restrict__ bf1,
    const __hip_bfloat16* __restrict__ Wf2_t, const float* __restrict__ bf2,
    const __hip_bfloat16* __restrict__ Wn_t,
    const float* __restrict__ W_out, const float* __restrict__ b_out,
    float* __restrict__ out)
{
    int row0 = blockIdx.x * 32;
    int t = threadIdx.x;
    int wave = t >> 6, lane = t & 63, lm = lane & 15, lq = lane >> 4;

    __shared__ __hip_bfloat16 AusT1[32*648]; // Aus (pitch 648); later t1=relu(FF1) (pitch 520)
    __shared__ float xs[32*132];             // fp32 working rows
    __shared__ __hip_bfloat16 yz[32*136];    // LN1 out, then LN2 out
    __hip_bfloat16* Aus = AusT1;
    __hip_bfloat16* t1  = AusT1;

    const __hip_bfloat16* Pbc = (const __hip_bfloat16*)P;
    for (int q = t; q < 2560; q += 512) {
        int r = q/80, c8 = (q%80)*8;
        int gr = row0 + r; if (gr > NROWS-1) gr = NROWS-1;
        *(s8v*)&Aus[r*648 + c8] = *(const s8v*)&Pbc[(size_t)gr*P_BF16_STRIDE + c8];
    }
    __syncthreads();

    // WoU: wave w -> n-tile w; weight frag reused across m-tiles 0/1
    {
        int cc = wave*16 + lm;
        f4v a0 = {0.f,0.f,0.f,0.f}, a1 = a0;
        for (int ks = 0; ks < 20; ks++) {
            s8v wf = *(const s8v*)&WoU_t[(size_t)(wave*16+lm)*640 + ks*32 + lq*8];
            s8v f0 = *(const s8v*)&Aus[lm*648 + ks*32 + lq*8];
            s8v f1 = *(const s8v*)&Aus[(16+lm)*648 + ks*32 + lq*8];
            a0 = __builtin_amdgcn_mfma_f32_16x16x32_bf16(f0, wf, a0, 0,0,0);
            a1 = __builtin_amdgcn_mfma_f32_16x16x32_bf16(f1, wf, a1, 0,0,0);
        }
#pragma unroll
        for (int r = 0; r < 4; r++) {
            int rr0 = lq*4 + r, rr1 = 16 + lq*4 + r;
            int g0 = row0 + rr0; if (g0 > NROWS-1) g0 = NROWS-1;
            int g1 = row0 + rr1; if (g1 > NROWS-1) g1 = NROWS-1;
            xs[rr0*132+cc] = hv[(size_t)g0*128 + cc] + a0[r];
            xs[rr1*132+cc] = hv[(size_t)g1*128 + cc] + a1[r];
        }
    }
    __syncthreads();

    // LN1: wave-parallel, 4 rows/wave, 64-lane butterfly
    {
        float g0 = ln1g[lane], g1 = ln1g[64+lane];
        float b0 = ln1b[lane], b1 = ln1b[64+lane];
#pragma unroll
        for (int i = 0; i < 4; i++) {
            int r = wave*4 + i;
            float x0 = xs[r*132 + lane], x1 = xs[r*132 + 64 + lane];
            float sm = x0 + x1, sq = x0*x0 + x1*x1;
#pragma unroll
            for (int m = 1; m < 64; m <<= 1) {
                sm += __shfl_xor(sm, m, 64);
                sq += __shfl_xor(sq, m, 64);
            }
            float mu = sm*(1.0f/H);
            float rs = rsqrtf(sq*(1.0f/H) - mu*mu + LN_EPS);
            float v0 = g0*(x0-mu)*rs + b0, v1 = g1*(x1-mu)*rs + b1;
            xs[r*132 + lane] = v0; xs[r*132 + 64 + lane] = v1;
            yz[r*136 + lane] = __float2bfloat16(v0);
            yz[r*136 + 64 + lane] = __float2bfloat16(v1);
        }
    }
    __syncthreads();

    // FF1: wave w -> n-tiles 4w..4w+3, frag reused across 2 m-tiles; t1 aliases Aus
    for (int ntl = 0; ntl < 4; ntl++) {
        int nt = wave*4 + ntl;
        int cc = nt*16 + lm;
        float b = bf1[cc];
        f4v a0 = {0.f,0.f,0.f,0.f}, a1 = a0;
#pragma unroll
        for (int ks = 0; ks < 4; ks++) {
            s8v wf = *(const s8v*)&Wf1_t[(size_t)(nt*16+lm)*128 + ks*32 + lq*8];
            s8v f0 = *(const s8v*)&yz[lm*136 + ks*32 + lq*8];
            s8v f1 = *(const s8v*)&yz[(16+lm)*136 + ks*32 + lq*8];
            a0 = __builtin_amdgcn_mfma_f32_16x16x32_bf16(f0, wf, a0, 0,0,0);
            a1 = __builtin_amdgcn_mfma_f32_16x16x32_bf16(f1, wf, a1, 0,0,0);
        }
#pragma unroll
        for (int r = 0; r < 4; r++) {
            t1[(lq*4+r)*520 + cc]      = __float2bfloat16(fmaxf(a0[r]+b, 0.f));
            t1[(16+lq*4+r)*520 + cc]   = __float2bfloat16(fmaxf(a1[r]+b, 0.f));
        }
    }
    __syncthreads();

    // FF2: wave w -> n-tile w, K=512
    {
        int cc = wave*16 + lm;
        float b = bf2[cc];
        f4v a0 = {0.f,0.f,0.f,0.f}, a1 = a0;
        for (int ks = 0; ks < 16; ks++) {
            s8v wf = *(const s8v*)&Wf2_t[(size_t)(wave*16+lm)*512 + ks*32 + lq*8];
            s8v f0 = *(const s8v*)&t1[lm*520 + ks*32 + lq*8];
            s8v f1 = *(const s8v*)&t1[(16+lm)*520 + ks*32 + lq*8];
            a0 = __builtin_amdgcn_mfma_f32_16x16x32_bf16(f0, wf, a0, 0,0,0);
            a1 = __builtin_amdgcn_mfma_f32_16x16x32_bf16(f1, wf, a1, 0,0,0);
        }
#pragma unroll
        for (int r = 0; r < 4; r++) {
            int rr0 = lq*4 + r, rr1 = 16 + lq*4 + r;
            xs[rr0*132+cc] = xs[rr0*132+cc] + a0[r] + b;
            xs[rr1*132+cc] = xs[rr1*132+cc] + a1[r] + b;
        }
    }
    __syncthreads();

    // LN2 + mask; write hv (guarded) + yz; final layer also computes out
    {
        float g0 = ln2g[lane], g1 = ln2g[64+lane];
        float b0 = ln2b[lane], b1 = ln2b[64+lane];
        float wo0 = 0.f, wo1 = 0.f, bo = 0.f;
        if (!Wn_t) { wo0 = W_out[lane]; wo1 = W_out[64+lane]; bo = b_out[0]; }
#pragma unroll
        for (int i = 0; i < 4; i++) {
            int r = wave*4 + i;
            int gr = row0 + r;
            float mk = mask[gr > NROWS-1 ? NROWS-1 : gr];
            float x0 = xs[r*132 + lane], x1 = xs[r*132 + 64 + lane];
            float sm = x0 + x1, sq = x0*x0 + x1*x1;
#pragma unroll
            for (int m = 1; m < 64; m <<= 1) {
                sm += __shfl_xor(sm, m, 64);
                sq += __shfl_xor(sq, m, 64);
            }
            float mu = sm*(1.0f/H);
            float rs = rsqrtf(sq*(1.0f/H) - mu*mu + LN_EPS);
            float v0 = mk*(g0*(x0-mu)*rs + b0), v1 = mk*(g1*(x1-mu)*rs + b1);
            yz[r*136 + lane] = __float2bfloat16(v0);
            yz[r*136 + 64 + lane] = __float2bfloat16(v1);
            if (gr < NROWS) {
                hv[(size_t)gr*128 + lane] = v0;
                hv[(size_t)gr*128 + 64 + lane] = v1;
            }
            if (!Wn_t) {
                float o = v0*wo0 + v1*wo1;
#pragma unroll
                for (int m = 1; m < 64; m <<= 1) o += __shfl_xor(o, m, 64);
                if (lane == 0 && gr < NROWS) out[gr] = o + bo;
            }
        }
    }
    __syncthreads();

    // next-layer node proj: 33 tiles over 8 waves (5 each, guard)
    if (Wn_t) {
        __hip_bfloat16* Pbw = (__hip_bfloat16*)P;
        for (int ntl = 0; ntl < 5; ntl++) {
            int nt = wave*5 + ntl;
            if (nt >= 33) break;
            int cc = nt*16 + lm;
            f4v a0 = {0.f,0.f,0.f,0.f}, a1 = a0;
#pragma unroll
            for (int ks = 0; ks < 4; ks++) {
                s8v wf = *(const s8v*)&Wn_t[(size_t)(nt*16+lm)*128 + ks*32 + lq*8];
                s8v f0 = *(const s8v*)&yz[lm*136 + ks*32 + lq*8];
                s8v f1 = *(const s8v*)&yz[(16+lm)*136 + ks*32 + lq*8];
                a0 = __builtin_amdgcn_mfma_f32_16x16x32_bf16(f0, wf, a0, 0,0,0);
                a1 = __builtin_amdgcn_mfma_f32_16x16x32_bf16(f1, wf, a1, 0,0,0);
            }
#pragma unroll
            for (int mt = 0; mt < 2; mt++) {
                f4v* ap = mt ? &a1 : &a0;
#pragma unroll
                for (int r = 0; r < 4; r++) {
                    int rr = row0 + mt*16 + lq*4 + r;
                    if (rr < NROWS) {
                        float av = (*ap)[r];
                        if (cc < 128)
                            P[(size_t)rr*P_F32_STRIDE + cc] = av;
                        else if (cc < 256)
                            Pbw[(size_t)rr*P_BF16_STRIDE + 640 + (cc-128)] = __float2bfloat16(av);
                        else if (cc < 272) {
                            if (cc < 260) qg_buf[rr*4 + (cc-256)] = av;
                        } else
                            PKV[(size_t)rr*256 + (cc-272)] = __float2bfloat16(av);
                    }
                }
            }
        }
    }
}

// ---------------------------------------------------------------- launch
extern "C" void kernel_launch(void* const* d_in, const int* in_sizes, int n_in,
                              void* d_out, int out_size, void* d_ws, size_t ws_size,
                              hipStream_t stream)
{
    const float* X      = (const float*)d_in[0];
    const float* V      = (const float*)d_in[1];
    const float* mask   = (const float*)d_in[2];
    const float* W_v    = (const float*)d_in[3];
    const float* b_v    = (const float*)d_in[4];
    const float* W_e    = (const float*)d_in[5];
    const float* b_e    = (const float*)d_in[6];
    const float* W_edge = (const float*)d_in[7];
    const float* ln_e_g = (const float*)d_in[8];
    const float* ln_e_b = (const float*)d_in[9];
    const float* Wq     = (const float*)d_in[10];
    const float* Wk     = (const float*)d_in[11];
    const float* Wv_a   = (const float*)d_in[12];
    const float* Wo     = (const float*)d_in[13];
    const float* ln1g   = (const float*)d_in[14];
    const float* ln1b   = (const float*)d_in[15];
    const float* ln2g   = (const float*)d_in[16];
    const float* ln2b   = (const float*)d_in[17];
    const float* Wf1    = (const float*)d_in[18];
    const float* bf1    = (const float*)d_in[19];
    const float* Wf2    = (const float*)d_in[20];
    const float* bf2    = (const float*)d_in[21];
    const float* W_out  = (const float*)d_in[22];
    const float* b_out  = (const float*)d_in[23];
    float* out = (float*)d_out;

    // workspace layout
    char* ws = (char*)d_ws;
    int*            E_idx    = (int*)ws;                                   //   720000
    float*          D_nb     = (float*)(ws + 720000);                      //   720000
    __hip_bfloat16* E_ln     = (__hip_bfloat16*)(ws + 1440000);            // 46080000
    float*          hv       = (float*)(ws + 47520000);                    //  3072000
    float*          bias_kv  = (float*)(ws + 50592000);                    //     4096
    float*          Wkv_f    = (float*)(ws + 50596096);                    //   524288
    __hip_bfloat16* Wn_t     = (__hip_bfloat16*)(ws + 51120384);           //   540672 used (917504 reserved)
    __hip_bfloat16* WoU_t    = (__hip_bfloat16*)(ws + 52037888);           //   655360
    __hip_bfloat16* Wf1_t    = (__hip_bfloat16*)(ws + 52693248);           //   524288
    __hip_bfloat16* Wf2_t    = (__hip_bfloat16*)(ws + 53217536);           //   524288
    __hip_bfloat16* Wv_t     = (__hip_bfloat16*)(ws + 53741824);           //   262144
    __hip_bfloat16* W_edge_t = (__hip_bfloat16*)(ws + 54003968);           //     8192
    __hip_bfloat16* PKV      = (__hip_bfloat16*)(ws + 54012160);           //  3072000
    float*          P        = (float*)(ws + 57084160);                    //  9216000
    float*          EMS      = (float*)(ws + 66300160);                    //  1440000
    float*          M_buf    = (float*)(ws + 67740160);                    //    65536
    float*          vg_buf   = (float*)(ws + 67805696);                    //     2048
    float*          qg_buf   = (float*)(ws + 67807744);                    //    96000

    topk_kernel<<<NROWS, 256, 0, stream>>>(X, mask, E_idx, D_nb);
    wprep_edge_kernel<<<16, 256, 0, stream>>>(W_edge, W_edge_t);
    edge_kernel<<<NROWS/2, 256, 0, stream>>>(E_idx, D_nb, W_edge_t, ln_e_g, ln_e_b, E_ln, EMS);
    wprep_kv_kernel<<<1024, 128, 0, stream>>>(W_e, b_e, Wk, Wv_a, Wkv_f, bias_kv);
    wprep_m_kernel<<<512, 128, 0, stream>>>(Wkv_f, W_edge, ln_e_g, M_buf, vg_buf);
    wprep_q2_kernel<<<512, 128, 0, stream>>>(Wq, M_buf, vg_buf, Wn_t);
    wprep_op_kernel<<<2560, 128, 0, stream>>>(Wo, Wkv_f, WoU_t);
    wprep_post_kernel<<<2816, 256, 0, stream>>>(Wf1, Wf2, Wq, Wk, Wv_a,
                                                Wf1_t, Wf2_t, Wn_t);
    wprep_v_kernel<<<512, 256, 0, stream>>>(W_v, Wv_t);
    hv_init_kernel<<<(NROWS+31)/32, 512, 0, stream>>>(V, Wv_t, b_v, hv, Wn_t, P, PKV, qg_buf);

    for (int l = 0; l < 4; l++) {
        attn_kernel<<<NROWS/2, 256, 0, stream>>>(
            E_ln, bias_kv + l*256 + 128, P, PKV, E_idx, D_nb, EMS, qg_buf, mask);
        post_kernel<<<(NROWS+31)/32, 512, 0, stream>>>(
            hv, P, PKV, qg_buf, mask, WoU_t + (size_t)l*81920,
            ln1g + l*H, ln1b + l*H, ln2g + l*H, ln2b + l*H,
            Wf1_t + (size_t)l*65536, bf1 + l*FFH,
            Wf2_t + (size_t)l*65536, bf2 + l*H,
            (l < 3) ? (Wn_t + (size_t)(l+1)*WNT_STRIDE) : (const __hip_bfloat16*)nullptr,
            W_out, b_out, out);
    }
}

// Round 14
// 417.822 us; speedup vs baseline: 1.0786x; 1.0786x over previous
//
#include <hip/hip_runtime.h>
#include <hip/hip_bf16.h>
#include <math.h>

#define NB 4
#define NN 1500
#define KNB 30
#define H 128
#define NHEADS 4
#define FFH 512
#define NODE_FEAT 1024
#define NROWS (NB*NN)
#define LN_EPS 1e-6f

// P layout per node: 1536 B = [Q f32 x128 | (bytes 1280..1535) Q'' bf16 x128];
// attn overwrites bf16 cols 0..639 with U = [Ebar(h*128+e) x512 | vpart x128].
#define P_F32_STRIDE 384
#define P_BF16_STRIDE 768

// Wn_t per-layer: 528 rows x 128 k (bf16). rows 0-127 Q, 128-255 Q'' (WQ2),
// 256-259 wqg, 260-271 zero pad, 272-399 Kbot, 400-527 Vbot.
#define WNT_STRIDE 67584

typedef __attribute__((ext_vector_type(8))) short s8v;   // 8 bf16 = 4 VGPRs (MFMA A/B frag)
typedef __attribute__((ext_vector_type(4))) float f4v;   // MFMA C/D frag

__device__ __forceinline__ float bf_lo(unsigned u){ union{unsigned i; float f;} v; v.i = u<<16; return v.f; }
__device__ __forceinline__ float bf_hi(unsigned u){ union{unsigned i; float f;} v; v.i = u & 0xffff0000u; return v.f; }

// ---------------------------------------------------------------- topk (radix select)
__device__ __forceinline__ void find_bucket30(
    const unsigned* hist, int base0, int t, int lane, int wave,
    int* wsum, int* res)
{
    int h[16], s = 0;
    const uint4* hp = (const uint4*)&hist[(t & 127) * 16];
    int sh = (t >> 7) << 4;
    uint4 w[4] = {hp[0], hp[1], hp[2], hp[3]};
#pragma unroll
    for (int i = 0; i < 4; i++) {
        h[i*4+0] = (w[i].x >> sh) & 0xffff;
        h[i*4+1] = (w[i].y >> sh) & 0xffff;
        h[i*4+2] = (w[i].z >> sh) & 0xffff;
        h[i*4+3] = (w[i].w >> sh) & 0xffff;
        s += h[i*4+0] + h[i*4+1] + h[i*4+2] + h[i*4+3];
    }
    int inc = s;
#pragma unroll
    for (int off = 1; off < 64; off <<= 1) {
        int o = __shfl_up(inc, off, 64);
        if (lane >= off) inc += o;
    }
    if (lane == 63) wsum[wave] = inc;
    __syncthreads();
    int base = base0 + inc - s;
    for (int w2 = 0; w2 < wave; w2++) base += wsum[w2];
    if (base < KNB && base + s >= KNB) {
        int running = base;
#pragma unroll
        for (int i = 0; i < 16; i++) {
            if (running < KNB && running + h[i] >= KNB) { res[0] = (t<<4)|i; res[1] = running; break; }
            running += h[i];
        }
    }
    __syncthreads();
}

__global__ __launch_bounds__(256) void topk_kernel(
    const float* __restrict__ X, const float* __restrict__ mask,
    int* __restrict__ E_idx, float* __restrict__ D_nb)
{
    int row = blockIdx.x;            // b*NN + i
    int b = row / NN;
    int t = threadIdx.x;
    int wave = t >> 6, lane = t & 63;
    __shared__ float d_adj[NN];
    __shared__ unsigned hist[2048];
    __shared__ float redw[4];
    __shared__ int   wsum[4];
    __shared__ int   res[2];
    __shared__ int   cand[64];
    __shared__ int   ncand;

    float xi0 = X[row*3+0], xi1 = X[row*3+1], xi2 = X[row*3+2];
    float mi = mask[row];

    float dr[6], m2r[6];
    float lmax = -1e30f;
#pragma unroll
    for (int q = 0; q < 6; q++) {
        int j = t + q*256;
        float d = 0.f, m2 = 0.f;
        if (j < NN) {
            float dx = xi0 - X[(b*NN+j)*3+0];
            float dy = xi1 - X[(b*NN+j)*3+1];
            float dz = xi2 - X[(b*NN+j)*3+2];
            d  = sqrtf(dx*dx + dy*dy + dz*dz + 1e-6f);
            m2 = mi * mask[b*NN+j];
            lmax = fmaxf(lmax, m2*d);
        }
        dr[q] = d; m2r[q] = m2;
    }
    for (int q = t; q < 2048; q += 256) hist[q] = 0;
#pragma unroll
    for (int off = 32; off > 0; off >>= 1)
        lmax = fmaxf(lmax, __shfl_xor(lmax, off, 64));
    if (lane == 0) redw[wave] = lmax;
    if (t == 0) ncand = 0;
    __syncthreads();
    float rowmax = fmaxf(fmaxf(redw[0], redw[1]), fmaxf(redw[2], redw[3]));

    unsigned kreg[6];
#pragma unroll
    for (int q = 0; q < 6; q++) {
        int j = t + q*256;
        if (j < NN) {
            float dv = m2r[q]*dr[q] + (1.0f - m2r[q])*rowmax;   // >= 0
            d_adj[j] = dv;
            unsigned key = __float_as_uint(dv);
            kreg[q] = key;
            unsigned bkt = key >> 20;
            atomicAdd(&hist[bkt & 2047], 1u << ((bkt >> 11) << 4));
        } else kreg[q] = 0xFFFFFFFFu;
    }
    __syncthreads();

    find_bucket30(hist, 0, t, lane, wave, wsum, res);
    int B1 = res[0], nb1 = res[1];

    for (int q = t; q < 2048; q += 256) hist[q] = 0;
    __syncthreads();
#pragma unroll
    for (int q = 0; q < 6; q++) {
        if ((kreg[q] >> 20) == (unsigned)B1) {
            unsigned bkt = (kreg[q] >> 8) & 0xFFF;
            atomicAdd(&hist[bkt & 2047], 1u << ((bkt >> 11) << 4));
        }
    }
    __syncthreads();

    find_bucket30(hist, nb1, t, lane, wave, wsum, res);
    unsigned Bfull = ((unsigned)B1 << 12) | (unsigned)res[0];

#pragma unroll
    for (int q = 0; q < 6; q++) {
        if ((kreg[q] >> 8) <= Bfull) {
            int slot = atomicAdd(&ncand, 1);
            if (slot < 64) cand[slot] = t + q*256;
        }
    }
    __syncthreads();

    if (wave == 0) {
        int nc = min(ncand, 64);
        if (lane < nc) {
            int j = cand[lane];
            float v = d_adj[j];
            int rank = 0;
            for (int m = 0; m < nc; m++) {
                int jm = cand[m];
                float vm = d_adj[jm];
                rank += (vm < v || (vm == v && jm < j)) ? 1 : 0;
            }
            if (rank < KNB) {
                E_idx[row*KNB + rank] = j;
                D_nb[row*KNB + rank]  = v;
            }
        }
    }
}

// ---------------------------------------------------------------- W_edge transpose+cast: W_edge_t[n][k] bf16 (128x32)
__global__ __launch_bounds__(256) void wprep_edge_kernel(
    const float* __restrict__ W_edge, __hip_bfloat16* __restrict__ W_edge_t)
{
    int tid = blockIdx.x*256 + threadIdx.x;  // 4096
    int n = tid >> 5, k = tid & 31;
    W_edge_t[tid] = __float2bfloat16(W_edge[k*H + n]);
}

// ---------------------------------------------------------------- edge features -> E_ln (bf16) + per-edge (rs, mu*rs), MFMA
__global__ __launch_bounds__(256) void edge_kernel(
    const int* __restrict__ E_idx, const float* __restrict__ D_nb,
    const __hip_bfloat16* __restrict__ W_edge_t, const float* __restrict__ ln_g,
    const float* __restrict__ ln_b, __hip_bfloat16* __restrict__ E_ln,
    float* __restrict__ EMS)
{
    int g0 = blockIdx.x * 2;
    int t = threadIdx.x;
    int wave = t >> 6, lane = t & 63, lm = lane & 15, lq = lane >> 4;
    __shared__ __hip_bfloat16 Es[64*136];

    int row = wave*16 + lm;
    int rr = row < 60 ? row : 59;
    int node = g0 + (rr >= KNB ? 1 : 0);
    int e = node*KNB + (rr >= KNB ? rr - KNB : rr);
    float drel = (float)(E_idx[e] - (node % NN));
    float dnb  = D_nb[e];

    const float FR[8] = {1.f, 0.31622776601683794f, 0.1f, 0.031622776601683794f,
                         0.01f, 0.0031622776601683794f, 0.001f, 0.00031622776601683794f};
    union { s8v v; __hip_bfloat16 h[8]; } af;
    if (lq == 0) {
#pragma unroll
        for (int j = 0; j < 8; j++) af.h[j] = __float2bfloat16(cosf(drel*FR[j]));
    } else if (lq == 1) {
#pragma unroll
        for (int j = 0; j < 8; j++) af.h[j] = __float2bfloat16(sinf(drel*FR[j]));
    } else {
        int f0 = (lq-2)*8;
#pragma unroll
        for (int j = 0; j < 8; j++) {
            float mu = (20.0f/15.0f) * (float)(f0+j);
            float z = (dnb - mu) * 0.8f;
            af.h[j] = __float2bfloat16(expf(-z*z));
        }
    }

    f4v acc[8];
#pragma unroll
    for (int nt = 0; nt < 8; nt++) {
        s8v bf = *(const s8v*)&W_edge_t[(nt*16+lm)*32 + lq*8];
        f4v z = {0.f,0.f,0.f,0.f};
        acc[nt] = __builtin_amdgcn_mfma_f32_16x16x32_bf16(af.v, bf, z, 0,0,0);
    }

    float gv[8], bv[8];
#pragma unroll
    for (int nt = 0; nt < 8; nt++) { gv[nt] = ln_g[nt*16+lm]; bv[nt] = ln_b[nt*16+lm]; }
#pragma unroll
    for (int r = 0; r < 4; r++) {
        float sm = 0.f, sq = 0.f;
#pragma unroll
        for (int nt = 0; nt < 8; nt++) { float x = acc[nt][r]; sm += x; sq += x*x; }
#pragma unroll
        for (int m = 1; m < 16; m <<= 1) {
            sm += __shfl_xor(sm, m, 64);
            sq += __shfl_xor(sq, m, 64);
        }
        float mu = sm * (1.0f/H);
        float rs = rsqrtf(sq*(1.0f/H) - mu*mu + LN_EPS);
        int erow = wave*16 + lq*4 + r;
        if (lm == 0 && erow < 60) {
            EMS[(g0*KNB + erow)*2]     = rs;
            EMS[(g0*KNB + erow)*2 + 1] = mu*rs;
        }
#pragma unroll
        for (int nt = 0; nt < 8; nt++)
            Es[erow*136 + nt*16 + lm] =
                __float2bfloat16(gv[nt]*(acc[nt][r]-mu)*rs + bv[nt]);
    }
    __syncthreads();

    __hip_bfloat16* dst = E_ln + (size_t)g0*KNB*H;
    for (int q = t; q < 960; q += 256) {
        int r = q >> 4, c8 = (q & 15) * 8;
        *(s8v*)&dst[r*H + c8] = *(const s8v*)&Es[r*136 + c8];
    }
}

// ---------------------------------------------------------------- W_v transpose+cast: Wv_t[n][k] bf16
__global__ __launch_bounds__(256) void wprep_v_kernel(
    const float* __restrict__ W_v, __hip_bfloat16* __restrict__ Wv_t)
{
    int tid = blockIdx.x*256 + threadIdx.x;  // 131072
    int n = tid & 127, k = tid >> 7;
    Wv_t[(size_t)n*NODE_FEAT + k] = __float2bfloat16(W_v[k*H + n]);
}

// ---------------------------------------------------------------- fold W_e into per-layer edge K/V (fp32, [l][col][e])
__global__ __launch_bounds__(128) void wprep_kv_kernel(
    const float* __restrict__ W_e, const float* __restrict__ b_e,
    const float* __restrict__ Wk, const float* __restrict__ Wv,
    float* __restrict__ Wkv_f, float* __restrict__ bias_kv)
{
    int l = blockIdx.x >> 8;
    int n = blockIdx.x & 255;
    int t = threadIdx.x;             // t = e (0..127)
    int col = n & 127;
    const float* W = (n < 128) ? (Wk + l*2*H*H) : (Wv + l*2*H*H);
    __shared__ float wcol[128];
    wcol[t] = W[t*H + col];          // rows 0..127 = h_E block
    __syncthreads();
    float a = 0.f;
    for (int c = 0; c < H; c += 4) {
        float4 we = *(const float4*)&W_e[t*H + c];
        a += we.x*wcol[c] + we.y*wcol[c+1] + we.z*wcol[c+2] + we.w*wcol[c+3];
    }
    Wkv_f[(size_t)(l*256 + n)*H + t] = a;   // Wek/Wev [e=t][col=n], stored [n][e]
    if (t == 0) {
        float bsum = 0.f;
        for (int c = 0; c < H; c++) bsum += b_e[c]*wcol[c];
        bias_kv[l*256 + n] = bsum;
    }
}

// ---------------------------------------------------------------- rank-32 fold part 1:
// M[l][n][f] = sum_e Wek[e][n]*g[e]*W_edge[f][e];  vg[l][n] = sum_e Wek[e][n]*g[e]
__global__ __launch_bounds__(128) void wprep_m_kernel(
    const float* __restrict__ Wkv_f, const float* __restrict__ W_edge,
    const float* __restrict__ ln_e_g,
    float* __restrict__ M_buf, float* __restrict__ vg_buf)
{
    int l = blockIdx.x >> 7;
    int n = blockIdx.x & 127;
    int t = threadIdx.x;
    __shared__ float wg_s[128];
    wg_s[t] = Wkv_f[(size_t)(l*256 + n)*H + t] * ln_e_g[t];
    __syncthreads();
    if (t < 32) {
        float a = 0.f;
        for (int e = 0; e < 128; e++) a += wg_s[e] * W_edge[t*H + e];
        M_buf[((size_t)(l*128 + n))*32 + t] = a;
    } else if (t == 32) {
        float a = 0.f;
        for (int e = 0; e < 128; e++) a += wg_s[e];
        vg_buf[l*128 + n] = a;
    }
}

// ---------------------------------------------------------------- rank-32 fold part 2:
// WQ2[l][c][h*32+f] = sum_d Wq[c][h32+d]*M[h32+d][f] -> Wn_t rows 128..255
// wqg[l][c][h]     = sum_d Wq[c][h32+d]*vg[h32+d]    -> Wn_t rows 256..259; 260..271 zero
__global__ __launch_bounds__(128) void wprep_q2_kernel(
    const float* __restrict__ Wq, const float* __restrict__ M_buf,
    const float* __restrict__ vg_buf, __hip_bfloat16* __restrict__ Wn_t)
{
    int l = blockIdx.x >> 7;
    int c = blockIdx.x & 127;
    int t = threadIdx.x;            // h*32+f
    int h = t >> 5, f = t & 31;
    __shared__ float wq_s[128];
    wq_s[t] = Wq[(size_t)l*16384 + c*128 + t];
    __syncthreads();
    float a = 0.f;
#pragma unroll
    for (int d = 0; d < 32; d++)
        a += wq_s[h*32 + d] * M_buf[((size_t)(l*128 + h*32 + d))*32 + f];
    Wn_t[(size_t)l*WNT_STRIDE + (128 + t)*H + c] = __float2bfloat16(a);
    if (t < 4) {
        float b = 0.f;
        for (int d = 0; d < 32; d++)
            b += wq_s[t*32 + d] * vg_buf[l*128 + t*32 + d];
        Wn_t[(size_t)l*WNT_STRIDE + (256 + t)*H + c] = __float2bfloat16(b);
    }
    if (t < 12) Wn_t[(size_t)l*WNT_STRIDE + (260 + t)*H + c] = __float2bfloat16(0.f);
}

// ---------------------------------------------------------------- WOP fold: WoU_t [l][n][k=640]
// k<512: sum_d Wev[e][h*32+d]*Wo[h*32+d][n];  k>=512: Wo[k-512][n]
__global__ __launch_bounds__(128) void wprep_op_kernel(
    const float* __restrict__ Wo, const float* __restrict__ Wkv_f,
    __hip_bfloat16* __restrict__ WoU_t)
{
    int l = blockIdx.x / 640;
    int kk = blockIdx.x - l*640;
    int n = threadIdx.x;
    __shared__ float wev[32];
    if (kk < 512) {
        int h = kk >> 7;
        int e = kk & 127;
        if (n < 32) wev[n] = Wkv_f[(size_t)(l*256 + 128 + h*32 + n)*H + e];
    }
    __syncthreads();
    float v;
    if (kk < 512) {
        int h = kk >> 7;
        float a = 0.f;
#pragma unroll
        for (int d = 0; d < 32; d++)
            a += wev[d]*Wo[(size_t)l*16384 + (h*32+d)*128 + n];
        v = a;
    } else {
        v = Wo[(size_t)l*16384 + (kk-512)*128 + n];
    }
    WoU_t[((size_t)l*128 + n)*640 + kk] = __float2bfloat16(v);
}

// ---------------------------------------------------------------- transpose+cast FF weights + Wn_t Q/Kbot/Vbot parts
__global__ __launch_bounds__(256) void wprep_post_kernel(
    const float* __restrict__ Wf1, const float* __restrict__ Wf2,
    const float* __restrict__ Wq, const float* __restrict__ Wk,
    const float* __restrict__ Wv,
    __hip_bfloat16* __restrict__ Wf1_t, __hip_bfloat16* __restrict__ Wf2_t,
    __hip_bfloat16* __restrict__ Wn_t)
{
    int id = blockIdx.x*256 + threadIdx.x;   // < 720896
    int l = id / 180224;
    int r = id - l*180224;
    float v; __hip_bfloat16* dst;
    if (r < 65536) {
        int n = r >> 7, k = r & 127;
        v = Wf1[(size_t)l*65536 + k*512 + n];
        dst = Wf1_t + (size_t)l*65536 + r;
    } else if (r < 131072) {
        int rr = r - 65536;
        int n = rr >> 9, k = rr & 511;
        v = Wf2[(size_t)l*65536 + k*128 + n];
        dst = Wf2_t + (size_t)l*65536 + rr;
    } else if (r < 147456) {
        int rr = r - 131072;                  // Q block: rows 0..127
        int n = rr >> 7, k = rr & 127;
        v = Wq[(size_t)l*16384 + k*128 + n];
        dst = Wn_t + (size_t)l*WNT_STRIDE + rr;
    } else {
        int rr = r - 147456;                  // Kbot/Vbot: n_local 0..255 -> rows 272..527
        int n = rr >> 7, k = rr & 127;
        v = (n < 128) ? Wk[(size_t)l*32768 + (128+k)*128 + n]
                      : Wv[(size_t)l*32768 + (128+k)*128 + (n-128)];
        dst = Wn_t + (size_t)l*WNT_STRIDE + 272*H + rr;
    }
    *dst = __float2bfloat16(v);
}

// ---------------------------------------------------------------- h_V = V @ W_v + b_v  (MFMA)
// + fused layer-0 node projections (33 tiles: Q | Q'' | qg | Kbot | Vbot)
__global__ __launch_bounds__(512) void hv_init_kernel(
    const float* __restrict__ V, const __hip_bfloat16* __restrict__ Wv_t,
    const float* __restrict__ b_v, float* __restrict__ hv,
    const __hip_bfloat16* __restrict__ Wn_t, float* __restrict__ P,
    __hip_bfloat16* __restrict__ PKV, float* __restrict__ qg_buf)
{
    int row0 = blockIdx.x * 32;
    int t = threadIdx.x;
    int wave = t >> 6, lane = t & 63, lm = lane & 15, lq = lane >> 4;
    __shared__ __hip_bfloat16 Vs[32*1032];   // pitch 1032 (2-way bank alias only)
    __shared__ __hip_bfloat16 zs[32*136];

    for (int q = t; q < 8192; q += 512) {
        int r = q >> 8, c4 = (q & 255) * 4;
        int gr = row0 + r; if (gr > NROWS-1) gr = NROWS-1;
        float4 v4 = *(const float4*)&V[(size_t)gr*NODE_FEAT + c4];
        union { ushort u[4]; uint2 w; } pk;
        pk.u[0] = __bfloat16_as_ushort(__float2bfloat16(v4.x));
        pk.u[1] = __bfloat16_as_ushort(__float2bfloat16(v4.y));
        pk.u[2] = __bfloat16_as_ushort(__float2bfloat16(v4.z));
        pk.u[3] = __bfloat16_as_ushort(__float2bfloat16(v4.w));
        *(uint2*)&Vs[r*1032 + c4] = pk.w;
    }
    __syncthreads();

    // h_V GEMM: wave w -> n-tile w; weight frag reused across m-tiles 0/1
    {
        int cc = wave*16 + lm;
        float b = b_v[cc];
        f4v a0 = {0.f,0.f,0.f,0.f}, a1 = a0;
        for (int ks = 0; ks < 32; ks++) {
            s8v wf = *(const s8v*)&Wv_t[(size_t)(wave*16+lm)*NODE_FEAT + ks*32 + lq*8];
            s8v f0 = *(const s8v*)&Vs[lm*1032 + ks*32 + lq*8];
            s8v f1 = *(const s8v*)&Vs[(16+lm)*1032 + ks*32 + lq*8];
            a0 = __builtin_amdgcn_mfma_f32_16x16x32_bf16(f0, wf, a0, 0,0,0);
            a1 = __builtin_amdgcn_mfma_f32_16x16x32_bf16(f1, wf, a1, 0,0,0);
        }
#pragma unroll
        for (int r = 0; r < 4; r++) {
            int rr0 = lq*4 + r, rr1 = 16 + lq*4 + r;
            int g0 = row0 + rr0, g1 = row0 + rr1;
            float v0 = a0[r] + b, v1 = a1[r] + b;
            if (g0 < NROWS) hv[(size_t)g0*H + cc] = v0;
            if (g1 < NROWS) hv[(size_t)g1*H + cc] = v1;
            zs[rr0*136+cc] = __float2bfloat16(v0);
            zs[rr1*136+cc] = __float2bfloat16(v1);
        }
    }
    __syncthreads();

    // layer-0 node projections: 33 tiles over 8 waves (5 each, guard)
    __hip_bfloat16* Pb = (__hip_bfloat16*)P;
    for (int ntl = 0; ntl < 5; ntl++) {
        int nt = wave*5 + ntl;
        if (nt >= 33) break;
        int cc = nt*16 + lm;
        f4v a0 = {0.f,0.f,0.f,0.f}, a1 = a0;
#pragma unroll
        for (int ks = 0; ks < 4; ks++) {
            s8v wf = *(const s8v*)&Wn_t[(size_t)(nt*16+lm)*H + ks*32 + lq*8];
            s8v f0 = *(const s8v*)&zs[lm*136 + ks*32 + lq*8];
            s8v f1 = *(const s8v*)&zs[(16+lm)*136 + ks*32 + lq*8];
            a0 = __builtin_amdgcn_mfma_f32_16x16x32_bf16(f0, wf, a0, 0,0,0);
            a1 = __builtin_amdgcn_mfma_f32_16x16x32_bf16(f1, wf, a1, 0,0,0);
        }
#pragma unroll
        for (int mt = 0; mt < 2; mt++) {
            f4v* ap = mt ? &a1 : &a0;
#pragma unroll
            for (int r = 0; r < 4; r++) {
                int rr = row0 + mt*16 + lq*4 + r;
                if (rr < NROWS) {
                    float av = (*ap)[r];
                    if (cc < 128)
                        P[(size_t)rr*P_F32_STRIDE + cc] = av;
                    else if (cc < 256)
                        Pb[(size_t)rr*P_BF16_STRIDE + 640 + (cc-128)] = __float2bfloat16(av);
                    else if (cc < 272) {
                        if (cc < 260) qg_buf[rr*4 + (cc-256)] = av;
                    } else
                        PKV[(size_t)rr*256 + (cc-272)] = __float2bfloat16(av);
                }
            }
        }
    }
}

// ---------------------------------------------------------------- attention: 2 nodes/block, 5-phase (proven shape).
// Rank-32 logits: logit_edge = rs*(Q''.Phi) - mu*rs*qg  (qb const-over-k cancels
// in softmax). Phi recomputed in-block with FAST-MATH trig (__cosf/__sinf/__expf
// = single v_cos/v_sin/v_exp instructions; R13's libm cosf/sinf was the
// regression: VALUBusy 48%). E_ln staged only for Ebar.
__global__ __launch_bounds__(256) void attn_kernel(
    const __hip_bfloat16* __restrict__ E_ln, const float* __restrict__ biasv,
    float* __restrict__ P, const __hip_bfloat16* __restrict__ PKV,
    const int* __restrict__ E_idx, const float* __restrict__ D_nb,
    const float* __restrict__ EMS, const float* __restrict__ qg_buf,
    const float* __restrict__ mask)
{
    int g0 = blockIdx.x * 2;
    int t = threadIdx.x;
    int wave = t >> 6, lane = t & 63, lm = lane & 15, lq = lane >> 4;
    __shared__ __hip_bfloat16 Es[60*136];    // E_ln rows (for Ebar), 16320 B
    __shared__ __hip_bfloat16 Ps[60*40];     // Phi rows (32 used), 4800 B
    __shared__ __hip_bfloat16 Qps[2*136];    // Q'' bf16 (128 used)
    __shared__ float Qs[2*128];              // Q f32
    __shared__ float att_s[2*128];           // [node][h*32+k]
    __shared__ float ssum[8];                // [node][h]
    __shared__ float mv_s[60];
    __shared__ float rs_s[60], murs_s[60];
    __shared__ float qgs[8];
    __shared__ int   nbr[60];

    const __hip_bfloat16* hebase = E_ln + (size_t)g0*KNB*H;
    for (int q = t; q < 960; q += 256) {
        int r = q >> 4, c8 = (q & 15) * 8;
        *(s8v*)&Es[r*136 + c8] = *(const s8v*)&hebase[r*H + c8];
    }
    const __hip_bfloat16* Pb = (const __hip_bfloat16*)P;
    if (t < 32) {
        int node = t >> 4, c8 = (t & 15)*8;
        *(s8v*)&Qps[node*136 + c8] = *(const s8v*)&Pb[(size_t)(g0+node)*P_BF16_STRIDE + 640 + c8];
    }
    {
        int node = t >> 7, c = t & 127;
        Qs[t] = P[(size_t)(g0+node)*P_F32_STRIDE + c];
    }
    if (t < 60) {
        int gn = g0 + t/30;
        int b = gn / NN;
        int idx = E_idx[gn*KNB + (t%30)];
        nbr[t]  = b*NN + idx;
        mv_s[t] = mask[gn] * mask[b*NN + idx];
        float2 em = ((const float2*)EMS)[g0*KNB + t];
        rs_s[t] = em.x; murs_s[t] = em.y;
    }
    if (t < 8) qgs[t] = qg_buf[(g0 + (t>>2))*4 + (t&3)];
    // Phi recompute: 4 threads per edge (seg = 8-dim slice), fast-math trig
    if (t < 240) {
        int r = t >> 2, seg = t & 3;
        int gn = g0 + r/30;
        int e = gn*KNB + (r%30);
        float drel = (float)(E_idx[e] - (gn % NN));
        float dnb  = D_nb[e];
        const float FR[8] = {1.f, 0.31622776601683794f, 0.1f, 0.031622776601683794f,
                             0.01f, 0.0031622776601683794f, 0.001f, 0.00031622776601683794f};
        union { s8v v; __hip_bfloat16 h[8]; } pf;
        if (seg == 0) {
#pragma unroll
            for (int j = 0; j < 8; j++) pf.h[j] = __float2bfloat16(__cosf(drel*FR[j]));
        } else if (seg == 1) {
#pragma unroll
            for (int j = 0; j < 8; j++) pf.h[j] = __float2bfloat16(__sinf(drel*FR[j]));
        } else {
            int f0 = (seg-2)*8;
#pragma unroll
            for (int j = 0; j < 8; j++) {
                float mu = (20.0f/15.0f) * (float)(f0+j);
                float z = (dnb - mu) * 0.8f;
                pf.h[j] = __float2bfloat16(__expf(-z*z));
            }
        }
        *(s8v*)&Ps[r*40 + seg*8] = pf.v;
    }
    __syncthreads();

    // logits: rank-32 edge dot + Kbot gather dot
    if (t < 240) {
        int node = t/120, tt = t%120, h = tt/30, kk = tt%30;
        int r = node*30 + kk;
        const uint4* pp = (const uint4*)&Ps[r*40];
        const uint4* qp = (const uint4*)&Qps[node*136 + h*32];
        float a = 0.f;
#pragma unroll
        for (int j = 0; j < 4; j++) {
            uint4 e4 = pp[j], q4 = qp[j];
            a += bf_lo(e4.x)*bf_lo(q4.x) + bf_hi(e4.x)*bf_hi(q4.x);
            a += bf_lo(e4.y)*bf_lo(q4.y) + bf_hi(e4.y)*bf_hi(q4.y);
            a += bf_lo(e4.z)*bf_lo(q4.z) + bf_hi(e4.z)*bf_hi(q4.z);
            a += bf_lo(e4.w)*bf_lo(q4.w) + bf_hi(e4.w)*bf_hi(q4.w);
        }
        a = rs_s[r]*a - murs_s[r]*qgs[node*4 + h];
        const uint4* kb = (const uint4*)(PKV + (size_t)nbr[r]*256 + h*32);
        const float* q = &Qs[node*128 + h*32];
#pragma unroll
        for (int j = 0; j < 4; j++) {
            uint4 u = kb[j];
            const float* q8 = q + j*8;
            a += q8[0]*bf_lo(u.x) + q8[1]*bf_hi(u.x)
               + q8[2]*bf_lo(u.y) + q8[3]*bf_hi(u.y)
               + q8[4]*bf_lo(u.z) + q8[5]*bf_hi(u.z)
               + q8[6]*bf_lo(u.w) + q8[7]*bf_hi(u.w);
        }
        att_s[node*128 + h*32 + kk] =
            (mv_s[r] > 0.f) ? a*0.17677669529663687f : -3.4028235e38f;
    }
    __syncthreads();

    // parallel softmax: wave w = node w (w<2), 16 lanes per head, 2 entries/lane
    if (wave < 2) {
        int node = wave, h = lq, j = lm;
        float* ap = &att_s[node*128 + h*32];
        const float* mp = &mv_s[node*30];
        float a0 = ap[j];
        float a1 = (j+16 < KNB) ? ap[j+16] : -3.4028235e38f;
        float mx = fmaxf(a0, a1);
#pragma unroll
        for (int m = 1; m < 16; m <<= 1) mx = fmaxf(mx, __shfl_xor(mx, m, 64));
        float e0 = __expf(a0 - mx);
        float e1 = (j+16 < KNB) ? __expf(a1 - mx) : 0.f;
        float s = e0 + e1;
#pragma unroll
        for (int m = 1; m < 16; m <<= 1) s += __shfl_xor(s, m, 64);
        float inv = 1.0f / s;
        float w0 = e0 * inv * mp[j];
        float w1 = (j+16 < KNB) ? e1 * inv * mp[j+16] : 0.f;
        ap[j] = w0;
        if (j+16 < KNB) ap[j+16] = w1;
        float ss = w0 + w1;
#pragma unroll
        for (int m = 1; m < 16; m <<= 1) ss += __shfl_xor(ss, m, 64);
        if (j == 0) ssum[node*4 + h] = ss;
    }
    __syncthreads();

    // U = [Ebar(512) | vpart(128)] bf16, written in-place over P node region
    {
        int node = t >> 7, c = t & 127, h = c >> 5;
        __hip_bfloat16* Ub = (__hip_bfloat16*)P + (size_t)(g0+node)*P_BF16_STRIDE;
        const float* ap = &att_s[node*128];
        const int* nb = &nbr[node*30];

        float u = ssum[node*4 + h] * biasv[c];
        const float* ah = ap + h*32;
        for (int k = 0; k < KNB; k++)
            u += ah[k] * __bfloat162float(PKV[(size_t)nb[k]*256 + 128 + c]);
        Ub[512 + c] = __float2bfloat16(u);

        float s0 = 0.f, s1 = 0.f, s2 = 0.f, s3 = 0.f;
        for (int k = 0; k < KNB; k++) {
            float e = __bfloat162float(Es[(node*30+k)*136 + c]);
            s0 += ap[k]      * e;
            s1 += ap[32+k]   * e;
            s2 += ap[64+k]   * e;
            s3 += ap[96+k]   * e;
        }
        Ub[c]       = __float2bfloat16(s0);
        Ub[128 + c] = __float2bfloat16(s1);
        Ub[256 + c] = __float2bfloat16(s2);
        Ub[384 + c] = __float2bfloat16(s3);
    }
}

// ---------------------------------------------------------------- WoU(K=640) + LN1 + FF + LN2 (+ next-layer node proj | out), MFMA
__global__ __launch_bounds__(512) void post_kernel(
    float* __restrict__ hv, float* __restrict__ P,
    __hip_bfloat16* __restrict__ PKV, float* __restrict__ qg_buf,
    const float* __restrict__ mask,
    const __hip_bfloat16* __restrict__ WoU_t,
    const float* __restrict__ ln1g, const float* __restrict__ ln1b,
    const float* __restrict__ ln2g, const float* __restrict__ ln2b,
    const __hip_bfloat16* __restrict__ Wf1_t, const float* __restrict__ bf1,
    const __hip_bfloat16* __restrict__ Wf2_t, const float* __restrict__ bf2,
    const __hip_bfloat16* __restrict__ Wn_t,
    const float* __restrict__ W_out, const float* __restrict__ b_out,
    float* __restrict__ out)
{
    int row0 = blockIdx.x * 32;
    int t = threadIdx.x;
    int wave = t >> 6, lane = t & 63, lm = lane & 15, lq = lane >> 4;

    __shared__ __hip_bfloat16 AusT1[32*648]; // Aus (pitch 648); later t1=relu(FF1) (pitch 520)
    __shared__ float xs[32*132];             // fp32 working rows
    __shared__ __hip_bfloat16 yz[32*136];    // LN1 out, then LN2 out
    __hip_bfloat16* Aus = AusT1;
    __hip_bfloat16* t1  = AusT1;

    const __hip_bfloat16* Pbc = (const __hip_bfloat16*)P;
    for (int q = t; q < 2560; q += 512) {
        int r = q/80, c8 = (q%80)*8;
        int gr = row0 + r; if (gr > NROWS-1) gr = NROWS-1;
        *(s8v*)&Aus[r*648 + c8] = *(const s8v*)&Pbc[(size_t)gr*P_BF16_STRIDE + c8];
    }
    __syncthreads();

    // WoU: wave w -> n-tile w; weight frag reused across m-tiles 0/1
    {
        int cc = wave*16 + lm;
        f4v a0 = {0.f,0.f,0.f,0.f}, a1 = a0;
        for (int ks = 0; ks < 20; ks++) {
            s8v wf = *(const s8v*)&WoU_t[(size_t)(wave*16+lm)*640 + ks*32 + lq*8];
            s8v f0 = *(const s8v*)&Aus[lm*648 + ks*32 + lq*8];
            s8v f1 = *(const s8v*)&Aus[(16+lm)*648 + ks*32 + lq*8];
            a0 = __builtin_amdgcn_mfma_f32_16x16x32_bf16(f0, wf, a0, 0,0,0);
            a1 = __builtin_amdgcn_mfma_f32_16x16x32_bf16(f1, wf, a1, 0,0,0);
        }
#pragma unroll
        for (int r = 0; r < 4; r++) {
            int rr0 = lq*4 + r, rr1 = 16 + lq*4 + r;
            int g0 = row0 + rr0; if (g0 > NROWS-1) g0 = NROWS-1;
            int g1 = row0 + rr1; if (g1 > NROWS-1) g1 = NROWS-1;
            xs[rr0*132+cc] = hv[(size_t)g0*128 + cc] + a0[r];
            xs[rr1*132+cc] = hv[(size_t)g1*128 + cc] + a1[r];
        }
    }
    __syncthreads();

    // LN1: wave-parallel, 4 rows/wave, 64-lane butterfly
    {
        float g0 = ln1g[lane], g1 = ln1g[64+lane];
        float b0 = ln1b[lane], b1 = ln1b[64+lane];
#pragma unroll
        for (int i = 0; i < 4; i++) {
            int r = wave*4 + i;
            float x0 = xs[r*132 + lane], x1 = xs[r*132 + 64 + lane];
            float sm = x0 + x1, sq = x0*x0 + x1*x1;
#pragma unroll
            for (int m = 1; m < 64; m <<= 1) {
                sm += __shfl_xor(sm, m, 64);
                sq += __shfl_xor(sq, m, 64);
            }
            float mu = sm*(1.0f/H);
            float rs = rsqrtf(sq*(1.0f/H) - mu*mu + LN_EPS);
            float v0 = g0*(x0-mu)*rs + b0, v1 = g1*(x1-mu)*rs + b1;
            xs[r*132 + lane] = v0; xs[r*132 + 64 + lane] = v1;
            yz[r*136 + lane] = __float2bfloat16(v0);
            yz[r*136 + 64 + lane] = __float2bfloat16(v1);
        }
    }
    __syncthreads();

    // FF1: wave w -> n-tiles 4w..4w+3, frag reused across 2 m-tiles; t1 aliases Aus
    for (int ntl = 0; ntl < 4; ntl++) {
        int nt = wave*4 + ntl;
        int cc = nt*16 + lm;
        float b = bf1[cc];
        f4v a0 = {0.f,0.f,0.f,0.f}, a1 = a0;
#pragma unroll
        for (int ks = 0; ks < 4; ks++) {
            s8v wf = *(const s8v*)&Wf1_t[(size_t)(nt*16+lm)*128 + ks*32 + lq*8];
            s8v f0 = *(const s8v*)&yz[lm*136 + ks*32 + lq*8];
            s8v f1 = *(const s8v*)&yz[(16+lm)*136 + ks*32 + lq*8];
            a0 = __builtin_amdgcn_mfma_f32_16x16x32_bf16(f0, wf, a0, 0,0,0);
            a1 = __builtin_amdgcn_mfma_f32_16x16x32_bf16(f1, wf, a1, 0,0,0);
        }
#pragma unroll
        for (int r = 0; r < 4; r++) {
            t1[(lq*4+r)*520 + cc]      = __float2bfloat16(fmaxf(a0[r]+b, 0.f));
            t1[(16+lq*4+r)*520 + cc]   = __float2bfloat16(fmaxf(a1[r]+b, 0.f));
        }
    }
    __syncthreads();

    // FF2: wave w -> n-tile w, K=512
    {
        int cc = wave*16 + lm;
        float b = bf2[cc];
        f4v a0 = {0.f,0.f,0.f,0.f}, a1 = a0;
        for (int ks = 0; ks < 16; ks++) {
            s8v wf = *(const s8v*)&Wf2_t[(size_t)(wave*16+lm)*512 + ks*32 + lq*8];
            s8v f0 = *(const s8v*)&t1[lm*520 + ks*32 + lq*8];
            s8v f1 = *(const s8v*)&t1[(16+lm)*520 + ks*32 + lq*8];
            a0 = __builtin_amdgcn_mfma_f32_16x16x32_bf16(f0, wf, a0, 0,0,0);
            a1 = __builtin_amdgcn_mfma_f32_16x16x32_bf16(f1, wf, a1, 0,0,0);
        }
#pragma unroll
        for (int r = 0; r < 4; r++) {
            int rr0 = lq*4 + r, rr1 = 16 + lq*4 + r;
            xs[rr0*132+cc] = xs[rr0*132+cc] + a0[r] + b;
            xs[rr1*132+cc] = xs[rr1*132+cc] + a1[r] + b;
        }
    }
    __syncthreads();

    // LN2 + mask; write hv (guarded) + yz; final layer also computes out
    {
        float g0 = ln2g[lane], g1 = ln2g[64+lane];
        float b0 = ln2b[lane], b1 = ln2b[64+lane];
        float wo0 = 0.f, wo1 = 0.f, bo = 0.f;
        if (!Wn_t) { wo0 = W_out[lane]; wo1 = W_out[64+lane]; bo = b_out[0]; }
#pragma unroll
        for (int i = 0; i < 4; i++) {
            int r = wave*4 + i;
            int gr = row0 + r;
            float mk = mask[gr > NROWS-1 ? NROWS-1 : gr];
            float x0 = xs[r*132 + lane], x1 = xs[r*132 + 64 + lane];
            float sm = x0 + x1, sq = x0*x0 + x1*x1;
#pragma unroll
            for (int m = 1; m < 64; m <<= 1) {
                sm += __shfl_xor(sm, m, 64);
                sq += __shfl_xor(sq, m, 64);
            }
            float mu = sm*(1.0f/H);
            float rs = rsqrtf(sq*(1.0f/H) - mu*mu + LN_EPS);
            float v0 = mk*(g0*(x0-mu)*rs + b0), v1 = mk*(g1*(x1-mu)*rs + b1);
            yz[r*136 + lane] = __float2bfloat16(v0);
            yz[r*136 + 64 + lane] = __float2bfloat16(v1);
            if (gr < NROWS) {
                hv[(size_t)gr*128 + lane] = v0;
                hv[(size_t)gr*128 + 64 + lane] = v1;
            }
            if (!Wn_t) {
                float o = v0*wo0 + v1*wo1;
#pragma unroll
                for (int m = 1; m < 64; m <<= 1) o += __shfl_xor(o, m, 64);
                if (lane == 0 && gr < NROWS) out[gr] = o + bo;
            }
        }
    }
    __syncthreads();

    // next-layer node proj: 33 tiles over 8 waves (5 each, guard)
    if (Wn_t) {
        __hip_bfloat16* Pbw = (__hip_bfloat16*)P;
        for (int ntl = 0; ntl < 5; ntl++) {
            int nt = wave*5 + ntl;
            if (nt >= 33) break;
            int cc = nt*16 + lm;
            f4v a0 = {0.f,0.f,0.f,0.f}, a1 = a0;
#pragma unroll
            for (int ks = 0; ks < 4; ks++) {
                s8v wf = *(const s8v*)&Wn_t[(size_t)(nt*16+lm)*128 + ks*32 + lq*8];
                s8v f0 = *(const s8v*)&yz[lm*136 + ks*32 + lq*8];
                s8v f1 = *(const s8v*)&yz[(16+lm)*136 + ks*32 + lq*8];
                a0 = __builtin_amdgcn_mfma_f32_16x16x32_bf16(f0, wf, a0, 0,0,0);
                a1 = __builtin_amdgcn_mfma_f32_16x16x32_bf16(f1, wf, a1, 0,0,0);
            }
#pragma unroll
            for (int mt = 0; mt < 2; mt++) {
                f4v* ap = mt ? &a1 : &a0;
#pragma unroll
                for (int r = 0; r < 4; r++) {
                    int rr = row0 + mt*16 + lq*4 + r;
                    if (rr < NROWS) {
                        float av = (*ap)[r];
                        if (cc < 128)
                            P[(size_t)rr*P_F32_STRIDE + cc] = av;
                        else if (cc < 256)
                            Pbw[(size_t)rr*P_BF16_STRIDE + 640 + (cc-128)] = __float2bfloat16(av);
                        else if (cc < 272) {
                            if (cc < 260) qg_buf[rr*4 + (cc-256)] = av;
                        } else
                            PKV[(size_t)rr*256 + (cc-272)] = __float2bfloat16(av);
                    }
                }
            }
        }
    }
}

// ---------------------------------------------------------------- launch
extern "C" void kernel_launch(void* const* d_in, const int* in_sizes, int n_in,
                              void* d_out, int out_size, void* d_ws, size_t ws_size,
                              hipStream_t stream)
{
    const float* X      = (const float*)d_in[0];
    const float* V      = (const float*)d_in[1];
    const float* mask   = (const float*)d_in[2];
    const float* W_v    = (const float*)d_in[3];
    const float* b_v    = (const float*)d_in[4];
    const float* W_e    = (const float*)d_in[5];
    const float* b_e    = (const float*)d_in[6];
    const float* W_edge = (const float*)d_in[7];
    const float* ln_e_g = (const float*)d_in[8];
    const float* ln_e_b = (const float*)d_in[9];
    const float* Wq     = (const float*)d_in[10];
    const float* Wk     = (const float*)d_in[11];
    const float* Wv_a   = (const float*)d_in[12];
    const float* Wo     = (const float*)d_in[13];
    const float* ln1g   = (const float*)d_in[14];
    const float* ln1b   = (const float*)d_in[15];
    const float* ln2g   = (const float*)d_in[16];
    const float* ln2b   = (const float*)d_in[17];
    const float* Wf1    = (const float*)d_in[18];
    const float* bf1    = (const float*)d_in[19];
    const float* Wf2    = (const float*)d_in[20];
    const float* bf2    = (const float*)d_in[21];
    const float* W_out  = (const float*)d_in[22];
    const float* b_out  = (const float*)d_in[23];
    float* out = (float*)d_out;

    // workspace layout
    char* ws = (char*)d_ws;
    int*            E_idx    = (int*)ws;                                   //   720000
    float*          D_nb     = (float*)(ws + 720000);                      //   720000
    __hip_bfloat16* E_ln     = (__hip_bfloat16*)(ws + 1440000);            // 46080000
    float*          hv       = (float*)(ws + 47520000);                    //  3072000
    float*          bias_kv  = (float*)(ws + 50592000);                    //     4096
    float*          Wkv_f    = (float*)(ws + 50596096);                    //   524288
    __hip_bfloat16* Wn_t     = (__hip_bfloat16*)(ws + 51120384);           //   540672 used (917504 reserved)
    __hip_bfloat16* WoU_t    = (__hip_bfloat16*)(ws + 52037888);           //   655360
    __hip_bfloat16* Wf1_t    = (__hip_bfloat16*)(ws + 52693248);           //   524288
    __hip_bfloat16* Wf2_t    = (__hip_bfloat16*)(ws + 53217536);           //   524288
    __hip_bfloat16* Wv_t     = (__hip_bfloat16*)(ws + 53741824);           //   262144
    __hip_bfloat16* W_edge_t = (__hip_bfloat16*)(ws + 54003968);           //     8192
    __hip_bfloat16* PKV      = (__hip_bfloat16*)(ws + 54012160);           //  3072000
    float*          P        = (float*)(ws + 57084160);                    //  9216000
    float*          EMS      = (float*)(ws + 66300160);                    //  1440000
    float*          M_buf    = (float*)(ws + 67740160);                    //    65536
    float*          vg_buf   = (float*)(ws + 67805696);                    //     2048
    float*          qg_buf   = (float*)(ws + 67807744);                    //    96000

    topk_kernel<<<NROWS, 256, 0, stream>>>(X, mask, E_idx, D_nb);
    wprep_edge_kernel<<<16, 256, 0, stream>>>(W_edge, W_edge_t);
    edge_kernel<<<NROWS/2, 256, 0, stream>>>(E_idx, D_nb, W_edge_t, ln_e_g, ln_e_b, E_ln, EMS);
    wprep_kv_kernel<<<1024, 128, 0, stream>>>(W_e, b_e, Wk, Wv_a, Wkv_f, bias_kv);
    wprep_m_kernel<<<512, 128, 0, stream>>>(Wkv_f, W_edge, ln_e_g, M_buf, vg_buf);
    wprep_q2_kernel<<<512, 128, 0, stream>>>(Wq, M_buf, vg_buf, Wn_t);
    wprep_op_kernel<<<2560, 128, 0, stream>>>(Wo, Wkv_f, WoU_t);
    wprep_post_kernel<<<2816, 256, 0, stream>>>(Wf1, Wf2, Wq, Wk, Wv_a,
                                                Wf1_t, Wf2_t, Wn_t);
    wprep_v_kernel<<<512, 256, 0, stream>>>(W_v, Wv_t);
    hv_init_kernel<<<(NROWS+31)/32, 512, 0, stream>>>(V, Wv_t, b_v, hv, Wn_t, P, PKV, qg_buf);

    for (int l = 0; l < 4; l++) {
        attn_kernel<<<NROWS/2, 256, 0, stream>>>(
            E_ln, bias_kv + l*256 + 128, P, PKV, E_idx, D_nb, EMS, qg_buf, mask);
        post_kernel<<<(NROWS+31)/32, 512, 0, stream>>>(
            hv, P, PKV, qg_buf, mask, WoU_t + (size_t)l*81920,
            ln1g + l*H, ln1b + l*H, ln2g + l*H, ln2b + l*H,
            Wf1_t + (size_t)l*65536, bf1 + l*FFH,
            Wf2_t + (size_t)l*65536, bf2 + l*H,
            (l < 3) ? (Wn_t + (size_t)(l+1)*WNT_STRIDE) : (const __hip_bfloat16*)nullptr,
            W_out, b_out, out);
    }
}

// Round 15
// 397.561 us; speedup vs baseline: 1.1336x; 1.0510x over previous
//
#include <hip/hip_runtime.h>
#include <hip/hip_bf16.h>
#include <math.h>

#define NB 4
#define NN 1500
#define KNB 30
#define H 128
#define NHEADS 4
#define FFH 512
#define NODE_FEAT 1024
#define NROWS (NB*NN)
#define LN_EPS 1e-6f

// P layout per node: 1536 B = [Q f32 x128 | (bytes 1280..1535) Q'' bf16 x128];
// attn overwrites bf16 cols 0..287 with U = [Phibar(h*32+f) x128 | sbar x4 |
// ss x4 | pad x8 | vpart x128 | pad x16].
#define P_F32_STRIDE 384
#define P_BF16_STRIDE 768
#define UK 288

// Wn_t per-layer: 528 rows x 128 k (bf16). rows 0-127 Q, 128-255 Q'' (WQ2),
// 256-259 wqg, 260-271 zero pad, 272-399 Kbot, 400-527 Vbot.
#define WNT_STRIDE 67584

typedef __attribute__((ext_vector_type(8))) short s8v;   // 8 bf16 = 4 VGPRs (MFMA A/B frag)
typedef __attribute__((ext_vector_type(4))) float f4v;   // MFMA C/D frag

__device__ __forceinline__ float bf_lo(unsigned u){ union{unsigned i; float f;} v; v.i = u<<16; return v.f; }
__device__ __forceinline__ float bf_hi(unsigned u){ union{unsigned i; float f;} v; v.i = u & 0xffff0000u; return v.f; }

// ---------------------------------------------------------------- topk (radix select)
__device__ __forceinline__ void find_bucket30(
    const unsigned* hist, int base0, int t, int lane, int wave,
    int* wsum, int* res)
{
    int h[16], s = 0;
    const uint4* hp = (const uint4*)&hist[(t & 127) * 16];
    int sh = (t >> 7) << 4;
    uint4 w[4] = {hp[0], hp[1], hp[2], hp[3]};
#pragma unroll
    for (int i = 0; i < 4; i++) {
        h[i*4+0] = (w[i].x >> sh) & 0xffff;
        h[i*4+1] = (w[i].y >> sh) & 0xffff;
        h[i*4+2] = (w[i].z >> sh) & 0xffff;
        h[i*4+3] = (w[i].w >> sh) & 0xffff;
        s += h[i*4+0] + h[i*4+1] + h[i*4+2] + h[i*4+3];
    }
    int inc = s;
#pragma unroll
    for (int off = 1; off < 64; off <<= 1) {
        int o = __shfl_up(inc, off, 64);
        if (lane >= off) inc += o;
    }
    if (lane == 63) wsum[wave] = inc;
    __syncthreads();
    int base = base0 + inc - s;
    for (int w2 = 0; w2 < wave; w2++) base += wsum[w2];
    if (base < KNB && base + s >= KNB) {
        int running = base;
#pragma unroll
        for (int i = 0; i < 16; i++) {
            if (running < KNB && running + h[i] >= KNB) { res[0] = (t<<4)|i; res[1] = running; break; }
            running += h[i];
        }
    }
    __syncthreads();
}

__global__ __launch_bounds__(256) void topk_kernel(
    const float* __restrict__ X, const float* __restrict__ mask,
    int* __restrict__ E_idx, float* __restrict__ D_nb)
{
    int row = blockIdx.x;            // b*NN + i
    int b = row / NN;
    int t = threadIdx.x;
    int wave = t >> 6, lane = t & 63;
    __shared__ float d_adj[NN];
    __shared__ unsigned hist[2048];
    __shared__ float redw[4];
    __shared__ int   wsum[4];
    __shared__ int   res[2];
    __shared__ int   cand[64];
    __shared__ int   ncand;

    float xi0 = X[row*3+0], xi1 = X[row*3+1], xi2 = X[row*3+2];
    float mi = mask[row];

    float dr[6], m2r[6];
    float lmax = -1e30f;
#pragma unroll
    for (int q = 0; q < 6; q++) {
        int j = t + q*256;
        float d = 0.f, m2 = 0.f;
        if (j < NN) {
            float dx = xi0 - X[(b*NN+j)*3+0];
            float dy = xi1 - X[(b*NN+j)*3+1];
            float dz = xi2 - X[(b*NN+j)*3+2];
            d  = sqrtf(dx*dx + dy*dy + dz*dz + 1e-6f);
            m2 = mi * mask[b*NN+j];
            lmax = fmaxf(lmax, m2*d);
        }
        dr[q] = d; m2r[q] = m2;
    }
    for (int q = t; q < 2048; q += 256) hist[q] = 0;
#pragma unroll
    for (int off = 32; off > 0; off >>= 1)
        lmax = fmaxf(lmax, __shfl_xor(lmax, off, 64));
    if (lane == 0) redw[wave] = lmax;
    if (t == 0) ncand = 0;
    __syncthreads();
    float rowmax = fmaxf(fmaxf(redw[0], redw[1]), fmaxf(redw[2], redw[3]));

    unsigned kreg[6];
#pragma unroll
    for (int q = 0; q < 6; q++) {
        int j = t + q*256;
        if (j < NN) {
            float dv = m2r[q]*dr[q] + (1.0f - m2r[q])*rowmax;   // >= 0
            d_adj[j] = dv;
            unsigned key = __float_as_uint(dv);
            kreg[q] = key;
            unsigned bkt = key >> 20;
            atomicAdd(&hist[bkt & 2047], 1u << ((bkt >> 11) << 4));
        } else kreg[q] = 0xFFFFFFFFu;
    }
    __syncthreads();

    find_bucket30(hist, 0, t, lane, wave, wsum, res);
    int B1 = res[0], nb1 = res[1];

    for (int q = t; q < 2048; q += 256) hist[q] = 0;
    __syncthreads();
#pragma unroll
    for (int q = 0; q < 6; q++) {
        if ((kreg[q] >> 20) == (unsigned)B1) {
            unsigned bkt = (kreg[q] >> 8) & 0xFFF;
            atomicAdd(&hist[bkt & 2047], 1u << ((bkt >> 11) << 4));
        }
    }
    __syncthreads();

    find_bucket30(hist, nb1, t, lane, wave, wsum, res);
    unsigned Bfull = ((unsigned)B1 << 12) | (unsigned)res[0];

#pragma unroll
    for (int q = 0; q < 6; q++) {
        if ((kreg[q] >> 8) <= Bfull) {
            int slot = atomicAdd(&ncand, 1);
            if (slot < 64) cand[slot] = t + q*256;
        }
    }
    __syncthreads();

    if (wave == 0) {
        int nc = min(ncand, 64);
        if (lane < nc) {
            int j = cand[lane];
            float v = d_adj[j];
            int rank = 0;
            for (int m = 0; m < nc; m++) {
                int jm = cand[m];
                float vm = d_adj[jm];
                rank += (vm < v || (vm == v && jm < j)) ? 1 : 0;
            }
            if (rank < KNB) {
                E_idx[row*KNB + rank] = j;
                D_nb[row*KNB + rank]  = v;
            }
        }
    }
}

// ---------------------------------------------------------------- W_edge transpose+cast: W_edge_t[n][k] bf16 (128x32)
__global__ __launch_bounds__(256) void wprep_edge_kernel(
    const float* __restrict__ W_edge, __hip_bfloat16* __restrict__ W_edge_t)
{
    int tid = blockIdx.x*256 + threadIdx.x;  // 4096
    int n = tid >> 5, k = tid & 31;
    W_edge_t[tid] = __float2bfloat16(W_edge[k*H + n]);
}

// ---------------------------------------------------------------- edge stats -> per-edge (rs, mu*rs) only, MFMA
// (E_ln no longer materialized anywhere: attn reconstructs everything from Phi.)
__global__ __launch_bounds__(256) void edge_kernel(
    const int* __restrict__ E_idx, const float* __restrict__ D_nb,
    const __hip_bfloat16* __restrict__ W_edge_t, float* __restrict__ EMS)
{
    int g0 = blockIdx.x * 2;
    int t = threadIdx.x;
    int wave = t >> 6, lane = t & 63, lm = lane & 15, lq = lane >> 4;

    int row = wave*16 + lm;
    int rr = row < 60 ? row : 59;
    int node = g0 + (rr >= KNB ? 1 : 0);
    int e = node*KNB + (rr >= KNB ? rr - KNB : rr);
    float drel = (float)(E_idx[e] - (node % NN));
    float dnb  = D_nb[e];

    const float FR[8] = {1.f, 0.31622776601683794f, 0.1f, 0.031622776601683794f,
                         0.01f, 0.0031622776601683794f, 0.001f, 0.00031622776601683794f};
    union { s8v v; __hip_bfloat16 h[8]; } af;
    if (lq == 0) {
#pragma unroll
        for (int j = 0; j < 8; j++) af.h[j] = __float2bfloat16(cosf(drel*FR[j]));
    } else if (lq == 1) {
#pragma unroll
        for (int j = 0; j < 8; j++) af.h[j] = __float2bfloat16(sinf(drel*FR[j]));
    } else {
        int f0 = (lq-2)*8;
#pragma unroll
        for (int j = 0; j < 8; j++) {
            float mu = (20.0f/15.0f) * (float)(f0+j);
            float z = (dnb - mu) * 0.8f;
            af.h[j] = __float2bfloat16(expf(-z*z));
        }
    }

    f4v acc[8];
#pragma unroll
    for (int nt = 0; nt < 8; nt++) {
        s8v bf = *(const s8v*)&W_edge_t[(nt*16+lm)*32 + lq*8];
        f4v z = {0.f,0.f,0.f,0.f};
        acc[nt] = __builtin_amdgcn_mfma_f32_16x16x32_bf16(af.v, bf, z, 0,0,0);
    }

#pragma unroll
    for (int r = 0; r < 4; r++) {
        float sm = 0.f, sq = 0.f;
#pragma unroll
        for (int nt = 0; nt < 8; nt++) { float x = acc[nt][r]; sm += x; sq += x*x; }
#pragma unroll
        for (int m = 1; m < 16; m <<= 1) {
            sm += __shfl_xor(sm, m, 64);
            sq += __shfl_xor(sq, m, 64);
        }
        float mu = sm * (1.0f/H);
        float rs = rsqrtf(sq*(1.0f/H) - mu*mu + LN_EPS);
        int erow = wave*16 + lq*4 + r;
        if (lm == 0 && erow < 60) {
            EMS[(g0*KNB + erow)*2]     = rs;
            EMS[(g0*KNB + erow)*2 + 1] = mu*rs;
        }
    }
}

// ---------------------------------------------------------------- W_v transpose+cast: Wv_t[n][k] bf16
__global__ __launch_bounds__(256) void wprep_v_kernel(
    const float* __restrict__ W_v, __hip_bfloat16* __restrict__ Wv_t)
{
    int tid = blockIdx.x*256 + threadIdx.x;  // 131072
    int n = tid & 127, k = tid >> 7;
    Wv_t[(size_t)n*NODE_FEAT + k] = __float2bfloat16(W_v[k*H + n]);
}

// ---------------------------------------------------------------- fold W_e into per-layer edge K/V (fp32, [l][col][e])
__global__ __launch_bounds__(128) void wprep_kv_kernel(
    const float* __restrict__ W_e, const float* __restrict__ b_e,
    const float* __restrict__ Wk, const float* __restrict__ Wv,
    float* __restrict__ Wkv_f, float* __restrict__ bias_kv)
{
    int l = blockIdx.x >> 8;
    int n = blockIdx.x & 255;
    int t = threadIdx.x;             // t = e (0..127)
    int col = n & 127;
    const float* W = (n < 128) ? (Wk + l*2*H*H) : (Wv + l*2*H*H);
    __shared__ float wcol[128];
    wcol[t] = W[t*H + col];          // rows 0..127 = h_E block
    __syncthreads();
    float a = 0.f;
    for (int c = 0; c < H; c += 4) {
        float4 we = *(const float4*)&W_e[t*H + c];
        a += we.x*wcol[c] + we.y*wcol[c+1] + we.z*wcol[c+2] + we.w*wcol[c+3];
    }
    Wkv_f[(size_t)(l*256 + n)*H + t] = a;   // Wek/Wev [e=t][col=n], stored [n][e]
    if (t == 0) {
        float bsum = 0.f;
        for (int c = 0; c < H; c++) bsum += b_e[c]*wcol[c];
        bias_kv[l*256 + n] = bsum;
    }
}

// ---------------------------------------------------------------- rank-32 fold part 1:
// M[l][n][f] = sum_e Wek[e][n]*g[e]*W_edge[f][e];  vg[l][n] = sum_e Wek[e][n]*g[e]
__global__ __launch_bounds__(128) void wprep_m_kernel(
    const float* __restrict__ Wkv_f, const float* __restrict__ W_edge,
    const float* __restrict__ ln_e_g,
    float* __restrict__ M_buf, float* __restrict__ vg_buf)
{
    int l = blockIdx.x >> 7;
    int n = blockIdx.x & 127;
    int t = threadIdx.x;
    __shared__ float wg_s[128];
    wg_s[t] = Wkv_f[(size_t)(l*256 + n)*H + t] * ln_e_g[t];
    __syncthreads();
    if (t < 32) {
        float a = 0.f;
        for (int e = 0; e < 128; e++) a += wg_s[e] * W_edge[t*H + e];
        M_buf[((size_t)(l*128 + n))*32 + t] = a;
    } else if (t == 32) {
        float a = 0.f;
        for (int e = 0; e < 128; e++) a += wg_s[e];
        vg_buf[l*128 + n] = a;
    }
}

// ---------------------------------------------------------------- rank-32 fold part 2:
// WQ2[l][c][h*32+f] = sum_d Wq[c][h32+d]*M[h32+d][f] -> Wn_t rows 128..255
// wqg[l][c][h]     = sum_d Wq[c][h32+d]*vg[h32+d]    -> Wn_t rows 256..259; 260..271 zero
__global__ __launch_bounds__(128) void wprep_q2_kernel(
    const float* __restrict__ Wq, const float* __restrict__ M_buf,
    const float* __restrict__ vg_buf, __hip_bfloat16* __restrict__ Wn_t)
{
    int l = blockIdx.x >> 7;
    int c = blockIdx.x & 127;
    int t = threadIdx.x;            // h*32+f
    int h = t >> 5, f = t & 31;
    __shared__ float wq_s[128];
    wq_s[t] = Wq[(size_t)l*16384 + c*128 + t];
    __syncthreads();
    float a = 0.f;
#pragma unroll
    for (int d = 0; d < 32; d++)
        a += wq_s[h*32 + d] * M_buf[((size_t)(l*128 + h*32 + d))*32 + f];
    Wn_t[(size_t)l*WNT_STRIDE + (128 + t)*H + c] = __float2bfloat16(a);
    if (t < 4) {
        float b = 0.f;
        for (int d = 0; d < 32; d++)
            b += wq_s[t*32 + d] * vg_buf[l*128 + t*32 + d];
        Wn_t[(size_t)l*WNT_STRIDE + (256 + t)*H + c] = __float2bfloat16(b);
    }
    if (t < 12) Wn_t[(size_t)l*WNT_STRIDE + (260 + t)*H + c] = __float2bfloat16(0.f);
}

// ---------------------------------------------------------------- Ebar fold: per (l,h,n):
// temp[e] = (Wev_h Wo)[e][n];  A_h[f][n]=sum_e W_edge[f][e] g[e] temp[e] -> k=h*32+f
// -u_h[n]=-sum_e g[e]temp[e] -> k=128+h;  w_h[n]=sum_e b[e]temp[e] -> k=132+h
__global__ __launch_bounds__(128) void wprep_op2_kernel(
    const float* __restrict__ Wo, const float* __restrict__ Wkv_f,
    const float* __restrict__ W_edge, const float* __restrict__ ln_e_g,
    const float* __restrict__ ln_e_b, __hip_bfloat16* __restrict__ WoU_t)
{
    int l = blockIdx.x >> 9;        // 4 x 4 x 128
    int hn = blockIdx.x & 511;
    int h = hn >> 7, n = hn & 127;
    int e = threadIdx.x;
    __shared__ float tg[128], tb[128];
    float tmp = 0.f;
    const float* wo = Wo + (size_t)l*16384 + (h*32)*128 + n;
    for (int d = 0; d < 32; d++)
        tmp += Wkv_f[(size_t)(l*256 + 128 + h*32 + d)*H + e] * wo[d*128];
    tg[e] = ln_e_g[e] * tmp;
    tb[e] = ln_e_b[e] * tmp;
    __syncthreads();
    if (e < 32) {
        float a = 0.f;
        for (int ee = 0; ee < 128; ee++) a += W_edge[e*H + ee] * tg[ee];
        WoU_t[((size_t)l*128 + n)*UK + h*32 + e] = __float2bfloat16(a);
    } else if (e == 32) {
        float a = 0.f, b = 0.f;
        for (int ee = 0; ee < 128; ee++) { a += tg[ee]; b += tb[ee]; }
        WoU_t[((size_t)l*128 + n)*UK + 128 + h] = __float2bfloat16(-a);
        WoU_t[((size_t)l*128 + n)*UK + 132 + h] = __float2bfloat16(b);
    }
}

// ---------------------------------------------------------------- WoU tail: k in [136,288): Wo rows at [144,272), zeros elsewhere
__global__ __launch_bounds__(128) void wprep_op_kernel(
    const float* __restrict__ Wo, __hip_bfloat16* __restrict__ WoU_t)
{
    int l = blockIdx.x / 152;
    int kk = 136 + (blockIdx.x % 152);
    int n = threadIdx.x;
    float v = 0.f;
    if (kk >= 144 && kk < 272) v = Wo[(size_t)l*16384 + (kk-144)*128 + n];
    WoU_t[((size_t)l*128 + n)*UK + kk] = __float2bfloat16(v);
}

// ---------------------------------------------------------------- transpose+cast FF weights + Wn_t Q/Kbot/Vbot parts
__global__ __launch_bounds__(256) void wprep_post_kernel(
    const float* __restrict__ Wf1, const float* __restrict__ Wf2,
    const float* __restrict__ Wq, const float* __restrict__ Wk,
    const float* __restrict__ Wv,
    __hip_bfloat16* __restrict__ Wf1_t, __hip_bfloat16* __restrict__ Wf2_t,
    __hip_bfloat16* __restrict__ Wn_t)
{
    int id = blockIdx.x*256 + threadIdx.x;   // < 720896
    int l = id / 180224;
    int r = id - l*180224;
    float v; __hip_bfloat16* dst;
    if (r < 65536) {
        int n = r >> 7, k = r & 127;
        v = Wf1[(size_t)l*65536 + k*512 + n];
        dst = Wf1_t + (size_t)l*65536 + r;
    } else if (r < 131072) {
        int rr = r - 65536;
        int n = rr >> 9, k = rr & 511;
        v = Wf2[(size_t)l*65536 + k*128 + n];
        dst = Wf2_t + (size_t)l*65536 + rr;
    } else if (r < 147456) {
        int rr = r - 131072;                  // Q block: rows 0..127
        int n = rr >> 7, k = rr & 127;
        v = Wq[(size_t)l*16384 + k*128 + n];
        dst = Wn_t + (size_t)l*WNT_STRIDE + rr;
    } else {
        int rr = r - 147456;                  // Kbot/Vbot: n_local 0..255 -> rows 272..527
        int n = rr >> 7, k = rr & 127;
        v = (n < 128) ? Wk[(size_t)l*32768 + (128+k)*128 + n]
                      : Wv[(size_t)l*32768 + (128+k)*128 + (n-128)];
        dst = Wn_t + (size_t)l*WNT_STRIDE + 272*H + rr;
    }
    *dst = __float2bfloat16(v);
}

// ---------------------------------------------------------------- h_V = V @ W_v + b_v  (MFMA)
// + fused layer-0 node projections (33 tiles: Q | Q'' | qg | Kbot | Vbot)
__global__ __launch_bounds__(512) void hv_init_kernel(
    const float* __restrict__ V, const __hip_bfloat16* __restrict__ Wv_t,
    const float* __restrict__ b_v, float* __restrict__ hv,
    const __hip_bfloat16* __restrict__ Wn_t, float* __restrict__ P,
    __hip_bfloat16* __restrict__ PKV, float* __restrict__ qg_buf)
{
    int row0 = blockIdx.x * 32;
    int t = threadIdx.x;
    int wave = t >> 6, lane = t & 63, lm = lane & 15, lq = lane >> 4;
    __shared__ __hip_bfloat16 Vs[32*1032];   // pitch 1032 (2-way bank alias only)
    __shared__ __hip_bfloat16 zs[32*136];

    for (int q = t; q < 8192; q += 512) {
        int r = q >> 8, c4 = (q & 255) * 4;
        int gr = row0 + r; if (gr > NROWS-1) gr = NROWS-1;
        float4 v4 = *(const float4*)&V[(size_t)gr*NODE_FEAT + c4];
        union { ushort u[4]; uint2 w; } pk;
        pk.u[0] = __bfloat16_as_ushort(__float2bfloat16(v4.x));
        pk.u[1] = __bfloat16_as_ushort(__float2bfloat16(v4.y));
        pk.u[2] = __bfloat16_as_ushort(__float2bfloat16(v4.z));
        pk.u[3] = __bfloat16_as_ushort(__float2bfloat16(v4.w));
        *(uint2*)&Vs[r*1032 + c4] = pk.w;
    }
    __syncthreads();

    // h_V GEMM: wave w -> n-tile w; weight frag reused across m-tiles 0/1
    {
        int cc = wave*16 + lm;
        float b = b_v[cc];
        f4v a0 = {0.f,0.f,0.f,0.f}, a1 = a0;
        for (int ks = 0; ks < 32; ks++) {
            s8v wf = *(const s8v*)&Wv_t[(size_t)(wave*16+lm)*NODE_FEAT + ks*32 + lq*8];
            s8v f0 = *(const s8v*)&Vs[lm*1032 + ks*32 + lq*8];
            s8v f1 = *(const s8v*)&Vs[(16+lm)*1032 + ks*32 + lq*8];
            a0 = __builtin_amdgcn_mfma_f32_16x16x32_bf16(f0, wf, a0, 0,0,0);
            a1 = __builtin_amdgcn_mfma_f32_16x16x32_bf16(f1, wf, a1, 0,0,0);
        }
#pragma unroll
        for (int r = 0; r < 4; r++) {
            int rr0 = lq*4 + r, rr1 = 16 + lq*4 + r;
            int g0 = row0 + rr0, g1 = row0 + rr1;
            float v0 = a0[r] + b, v1 = a1[r] + b;
            if (g0 < NROWS) hv[(size_t)g0*H + cc] = v0;
            if (g1 < NROWS) hv[(size_t)g1*H + cc] = v1;
            zs[rr0*136+cc] = __float2bfloat16(v0);
            zs[rr1*136+cc] = __float2bfloat16(v1);
        }
    }
    __syncthreads();

    // layer-0 node projections: 33 tiles over 8 waves (5 each, guard)
    __hip_bfloat16* Pb = (__hip_bfloat16*)P;
    for (int ntl = 0; ntl < 5; ntl++) {
        int nt = wave*5 + ntl;
        if (nt >= 33) break;
        int cc = nt*16 + lm;
        f4v a0 = {0.f,0.f,0.f,0.f}, a1 = a0;
#pragma unroll
        for (int ks = 0; ks < 4; ks++) {
            s8v wf = *(const s8v*)&Wn_t[(size_t)(nt*16+lm)*H + ks*32 + lq*8];
            s8v f0 = *(const s8v*)&zs[lm*136 + ks*32 + lq*8];
            s8v f1 = *(const s8v*)&zs[(16+lm)*136 + ks*32 + lq*8];
            a0 = __builtin_amdgcn_mfma_f32_16x16x32_bf16(f0, wf, a0, 0,0,0);
            a1 = __builtin_amdgcn_mfma_f32_16x16x32_bf16(f1, wf, a1, 0,0,0);
        }
#pragma unroll
        for (int mt = 0; mt < 2; mt++) {
            f4v* ap = mt ? &a1 : &a0;
#pragma unroll
            for (int r = 0; r < 4; r++) {
                int rr = row0 + mt*16 + lq*4 + r;
                if (rr < NROWS) {
                    float av = (*ap)[r];
                    if (cc < 128)
                        P[(size_t)rr*P_F32_STRIDE + cc] = av;
                    else if (cc < 256)
                        Pb[(size_t)rr*P_BF16_STRIDE + 640 + (cc-128)] = __float2bfloat16(av);
                    else if (cc < 272) {
                        if (cc < 260) qg_buf[rr*4 + (cc-256)] = av;
                    } else
                        PKV[(size_t)rr*256 + (cc-272)] = __float2bfloat16(av);
                }
            }
        }
    }
}

// ---------------------------------------------------------------- attention: 2 nodes/block, 5-phase (proven shape).
// Rank-32 logits AND rank-32 Ebar: no E_ln anywhere. Phi recomputed with
// fast-math trig. U = [Phibar x128 | sbar x4 | ss x4 | 0 x8 | vpart x128 | 0 x16].
__global__ __launch_bounds__(256) void attn_kernel(
    const float* __restrict__ biasv,
    float* __restrict__ P, const __hip_bfloat16* __restrict__ PKV,
    const int* __restrict__ E_idx, const float* __restrict__ D_nb,
    const float* __restrict__ EMS, const float* __restrict__ qg_buf,
    const float* __restrict__ mask)
{
    int g0 = blockIdx.x * 2;
    int t = threadIdx.x;
    int wave = t >> 6, lane = t & 63, lm = lane & 15, lq = lane >> 4;
    __shared__ __hip_bfloat16 Ps[60*40];     // Phi rows (32 used), 4800 B
    __shared__ __hip_bfloat16 Qps[2*136];    // Q'' bf16 (128 used)
    __shared__ float Qs[2*128];              // Q f32
    __shared__ float att_s[2*128];           // [node][h*32+k]
    __shared__ float ssum[8];                // [node][h]
    __shared__ float mv_s[60];
    __shared__ float rs_s[60], murs_s[60];
    __shared__ float qgs[8];
    __shared__ int   nbr[60];

    const __hip_bfloat16* Pb = (const __hip_bfloat16*)P;
    if (t < 32) {
        int node = t >> 4, c8 = (t & 15)*8;
        *(s8v*)&Qps[node*136 + c8] = *(const s8v*)&Pb[(size_t)(g0+node)*P_BF16_STRIDE + 640 + c8];
    }
    {
        int node = t >> 7, c = t & 127;
        Qs[t] = P[(size_t)(g0+node)*P_F32_STRIDE + c];
    }
    if (t < 60) {
        int gn = g0 + t/30;
        int b = gn / NN;
        int idx = E_idx[gn*KNB + (t%30)];
        nbr[t]  = b*NN + idx;
        mv_s[t] = mask[gn] * mask[b*NN + idx];
        float2 em = ((const float2*)EMS)[g0*KNB + t];
        rs_s[t] = em.x; murs_s[t] = em.y;
    }
    if (t < 8) qgs[t] = qg_buf[(g0 + (t>>2))*4 + (t&3)];
    // Phi recompute: 4 threads per edge (seg = 8-dim slice), fast-math trig
    if (t < 240) {
        int r = t >> 2, seg = t & 3;
        int gn = g0 + r/30;
        int e = gn*KNB + (r%30);
        float drel = (float)(E_idx[e] - (gn % NN));
        float dnb  = D_nb[e];
        const float FR[8] = {1.f, 0.31622776601683794f, 0.1f, 0.031622776601683794f,
                             0.01f, 0.0031622776601683794f, 0.001f, 0.00031622776601683794f};
        union { s8v v; __hip_bfloat16 h[8]; } pf;
        if (seg == 0) {
#pragma unroll
            for (int j = 0; j < 8; j++) pf.h[j] = __float2bfloat16(__cosf(drel*FR[j]));
        } else if (seg == 1) {
#pragma unroll
            for (int j = 0; j < 8; j++) pf.h[j] = __float2bfloat16(__sinf(drel*FR[j]));
        } else {
            int f0 = (seg-2)*8;
#pragma unroll
            for (int j = 0; j < 8; j++) {
                float mu = (20.0f/15.0f) * (float)(f0+j);
                float z = (dnb - mu) * 0.8f;
                pf.h[j] = __float2bfloat16(__expf(-z*z));
            }
        }
        *(s8v*)&Ps[r*40 + seg*8] = pf.v;
    }
    __syncthreads();

    // logits: rank-32 edge dot + Kbot gather dot
    if (t < 240) {
        int node = t/120, tt = t%120, h = tt/30, kk = tt%30;
        int r = node*30 + kk;
        const uint4* pp = (const uint4*)&Ps[r*40];
        const uint4* qp = (const uint4*)&Qps[node*136 + h*32];
        float a = 0.f;
#pragma unroll
        for (int j = 0; j < 4; j++) {
            uint4 e4 = pp[j], q4 = qp[j];
            a += bf_lo(e4.x)*bf_lo(q4.x) + bf_hi(e4.x)*bf_hi(q4.x);
            a += bf_lo(e4.y)*bf_lo(q4.y) + bf_hi(e4.y)*bf_hi(q4.y);
            a += bf_lo(e4.z)*bf_lo(q4.z) + bf_hi(e4.z)*bf_hi(q4.z);
            a += bf_lo(e4.w)*bf_lo(q4.w) + bf_hi(e4.w)*bf_hi(q4.w);
        }
        a = rs_s[r]*a - murs_s[r]*qgs[node*4 + h];
        const uint4* kb = (const uint4*)(PKV + (size_t)nbr[r]*256 + h*32);
        const float* q = &Qs[node*128 + h*32];
#pragma unroll
        for (int j = 0; j < 4; j++) {
            uint4 u = kb[j];
            const float* q8 = q + j*8;
            a += q8[0]*bf_lo(u.x) + q8[1]*bf_hi(u.x)
               + q8[2]*bf_lo(u.y) + q8[3]*bf_hi(u.y)
               + q8[4]*bf_lo(u.z) + q8[5]*bf_hi(u.z)
               + q8[6]*bf_lo(u.w) + q8[7]*bf_hi(u.w);
        }
        att_s[node*128 + h*32 + kk] =
            (mv_s[r] > 0.f) ? a*0.17677669529663687f : -3.4028235e38f;
    }
    __syncthreads();

    // parallel softmax: wave w = node w (w<2), 16 lanes per head, 2 entries/lane
    if (wave < 2) {
        int node = wave, h = lq, j = lm;
        float* ap = &att_s[node*128 + h*32];
        const float* mp = &mv_s[node*30];
        float a0 = ap[j];
        float a1 = (j+16 < KNB) ? ap[j+16] : -3.4028235e38f;
        float mx = fmaxf(a0, a1);
#pragma unroll
        for (int m = 1; m < 16; m <<= 1) mx = fmaxf(mx, __shfl_xor(mx, m, 64));
        float e0 = __expf(a0 - mx);
        float e1 = (j+16 < KNB) ? __expf(a1 - mx) : 0.f;
        float s = e0 + e1;
#pragma unroll
        for (int m = 1; m < 16; m <<= 1) s += __shfl_xor(s, m, 64);
        float inv = 1.0f / s;
        float w0 = e0 * inv * mp[j];
        float w1 = (j+16 < KNB) ? e1 * inv * mp[j+16] : 0.f;
        ap[j] = w0;
        if (j+16 < KNB) ap[j+16] = w1;
        float ss = w0 + w1;
#pragma unroll
        for (int m = 1; m < 16; m <<= 1) ss += __shfl_xor(ss, m, 64);
        if (j == 0) ssum[node*4 + h] = ss;
    }
    __syncthreads();

    // U = [Phibar | sbar | ss | 0 | vpart | 0] bf16 over P node region
    {
        int node = t >> 7, c = t & 127, h = c >> 5, f = c & 31;
        __hip_bfloat16* Ub = (__hip_bfloat16*)P + (size_t)(g0+node)*P_BF16_STRIDE;
        const float* ap = &att_s[node*128];
        const int* nb = &nbr[node*30];
        const float* ah = ap + h*32;

        // vpart col c
        float u = ssum[node*4 + h] * biasv[c];
        for (int k = 0; k < KNB; k++)
            u += ah[k] * __bfloat162float(PKV[(size_t)nb[k]*256 + 128 + c]);
        Ub[144 + c] = __float2bfloat16(u);

        // Phibar element (h, f)
        float pb = 0.f;
        for (int k = 0; k < KNB; k++)
            pb += ah[k] * rs_s[node*30+k] * __bfloat162float(Ps[(node*30+k)*40 + f]);
        Ub[c] = __float2bfloat16(pb);

        if (c < 4) {                 // sbar_h, ss_h for h=c
            const float* ah2 = ap + c*32;
            float sb = 0.f;
            for (int k = 0; k < KNB; k++) sb += ah2[k] * murs_s[node*30+k];
            Ub[128 + c] = __float2bfloat16(sb);
            Ub[132 + c] = __float2bfloat16(ssum[node*4 + c]);
        }
        if (c < 8)  Ub[136 + c] = __float2bfloat16(0.f);
        if (c >= 8 && c < 24) Ub[264 + c] = __float2bfloat16(0.f);   // 272..287
    }
}

// ---------------------------------------------------------------- WoU(K=288) + LN1 + FF + LN2 (+ next-layer node proj | out), MFMA
__global__ __launch_bounds__(512) void post_kernel(
    float* __restrict__ hv, float* __restrict__ P,
    __hip_bfloat16* __restrict__ PKV, float* __restrict__ qg_buf,
    const float* __restrict__ mask,
    const __hip_bfloat16* __restrict__ WoU_t,
    const float* __restrict__ ln1g, const float* __restrict__ ln1b,
    const float* __restrict__ ln2g, const float* __restrict__ ln2b,
    const __hip_bfloat16* __restrict__ Wf1_t, const float* __restrict__ bf1,
    const __hip_bfloat16* __restrict__ Wf2_t, const float* __restrict__ bf2,
    const __hip_bfloat16* __restrict__ Wn_t,
    const float* __restrict__ W_out, const float* __restrict__ b_out,
    float* __restrict__ out)
{
    int row0 = blockIdx.x * 32;
    int t = threadIdx.x;
    int wave = t >> 6, lane = t & 63, lm = lane & 15, lq = lane >> 4;

    __shared__ __hip_bfloat16 AusT1[32*520]; // Aus (pitch 296); later t1=relu(FF1) (pitch 520)
    __shared__ float xs[32*132];             // fp32 working rows
    __shared__ __hip_bfloat16 yz[32*136];    // LN1 out, then LN2 out
    __hip_bfloat16* Aus = AusT1;
    __hip_bfloat16* t1  = AusT1;

    const __hip_bfloat16* Pbc = (const __hip_bfloat16*)P;
    for (int q = t; q < 1152; q += 512) {
        int r = q/36, c8 = (q%36)*8;
        int gr = row0 + r; if (gr > NROWS-1) gr = NROWS-1;
        *(s8v*)&Aus[r*296 + c8] = *(const s8v*)&Pbc[(size_t)gr*P_BF16_STRIDE + c8];
    }
    __syncthreads();

    // WoU: wave w -> n-tile w; K=288 (9 ks); weight frag reused across m-tiles 0/1
    {
        int cc = wave*16 + lm;
        f4v a0 = {0.f,0.f,0.f,0.f}, a1 = a0;
        for (int ks = 0; ks < 9; ks++) {
            s8v wf = *(const s8v*)&WoU_t[(size_t)(wave*16+lm)*UK + ks*32 + lq*8];
            s8v f0 = *(const s8v*)&Aus[lm*296 + ks*32 + lq*8];
            s8v f1 = *(const s8v*)&Aus[(16+lm)*296 + ks*32 + lq*8];
            a0 = __builtin_amdgcn_mfma_f32_16x16x32_bf16(f0, wf, a0, 0,0,0);
            a1 = __builtin_amdgcn_mfma_f32_16x16x32_bf16(f1, wf, a1, 0,0,0);
        }
#pragma unroll
        for (int r = 0; r < 4; r++) {
            int rr0 = lq*4 + r, rr1 = 16 + lq*4 + r;
            int g0 = row0 + rr0; if (g0 > NROWS-1) g0 = NROWS-1;
            int g1 = row0 + rr1; if (g1 > NROWS-1) g1 = NROWS-1;
            xs[rr0*132+cc] = hv[(size_t)g0*128 + cc] + a0[r];
            xs[rr1*132+cc] = hv[(size_t)g1*128 + cc] + a1[r];
        }
    }
    __syncthreads();

    // LN1: wave-parallel, 4 rows/wave, 64-lane butterfly
    {
        float g0 = ln1g[lane], g1 = ln1g[64+lane];
        float b0 = ln1b[lane], b1 = ln1b[64+lane];
#pragma unroll
        for (int i = 0; i < 4; i++) {
            int r = wave*4 + i;
            float x0 = xs[r*132 + lane], x1 = xs[r*132 + 64 + lane];
            float sm = x0 + x1, sq = x0*x0 + x1*x1;
#pragma unroll
            for (int m = 1; m < 64; m <<= 1) {
                sm += __shfl_xor(sm, m, 64);
                sq += __shfl_xor(sq, m, 64);
            }
            float mu = sm*(1.0f/H);
            float rs = rsqrtf(sq*(1.0f/H) - mu*mu + LN_EPS);
            float v0 = g0*(x0-mu)*rs + b0, v1 = g1*(x1-mu)*rs + b1;
            xs[r*132 + lane] = v0; xs[r*132 + 64 + lane] = v1;
            yz[r*136 + lane] = __float2bfloat16(v0);
            yz[r*136 + 64 + lane] = __float2bfloat16(v1);
        }
    }
    __syncthreads();

    // FF1: wave w -> n-tiles 4w..4w+3, frag reused across 2 m-tiles; t1 aliases Aus
    for (int ntl = 0; ntl < 4; ntl++) {
        int nt = wave*4 + ntl;
        int cc = nt*16 + lm;
        float b = bf1[cc];
        f4v a0 = {0.f,0.f,0.f,0.f}, a1 = a0;
#pragma unroll
        for (int ks = 0; ks < 4; ks++) {
            s8v wf = *(const s8v*)&Wf1_t[(size_t)(nt*16+lm)*128 + ks*32 + lq*8];
            s8v f0 = *(const s8v*)&yz[lm*136 + ks*32 + lq*8];
            s8v f1 = *(const s8v*)&yz[(16+lm)*136 + ks*32 + lq*8];
            a0 = __builtin_amdgcn_mfma_f32_16x16x32_bf16(f0, wf, a0, 0,0,0);
            a1 = __builtin_amdgcn_mfma_f32_16x16x32_bf16(f1, wf, a1, 0,0,0);
        }
#pragma unroll
        for (int r = 0; r < 4; r++) {
            t1[(lq*4+r)*520 + cc]      = __float2bfloat16(fmaxf(a0[r]+b, 0.f));
            t1[(16+lq*4+r)*520 + cc]   = __float2bfloat16(fmaxf(a1[r]+b, 0.f));
        }
    }
    __syncthreads();

    // FF2: wave w -> n-tile w, K=512
    {
        int cc = wave*16 + lm;
        float b = bf2[cc];
        f4v a0 = {0.f,0.f,0.f,0.f}, a1 = a0;
        for (int ks = 0; ks < 16; ks++) {
            s8v wf = *(const s8v*)&Wf2_t[(size_t)(wave*16+lm)*512 + ks*32 + lq*8];
            s8v f0 = *(const s8v*)&t1[lm*520 + ks*32 + lq*8];
            s8v f1 = *(const s8v*)&t1[(16+lm)*520 + ks*32 + lq*8];
            a0 = __builtin_amdgcn_mfma_f32_16x16x32_bf16(f0, wf, a0, 0,0,0);
            a1 = __builtin_amdgcn_mfma_f32_16x16x32_bf16(f1, wf, a1, 0,0,0);
        }
#pragma unroll
        for (int r = 0; r < 4; r++) {
            int rr0 = lq*4 + r, rr1 = 16 + lq*4 + r;
            xs[rr0*132+cc] = xs[rr0*132+cc] + a0[r] + b;
            xs[rr1*132+cc] = xs[rr1*132+cc] + a1[r] + b;
        }
    }
    __syncthreads();

    // LN2 + mask; write hv (guarded) + yz; final layer also computes out
    {
        float g0 = ln2g[lane], g1 = ln2g[64+lane];
        float b0 = ln2b[lane], b1 = ln2b[64+lane];
        float wo0 = 0.f, wo1 = 0.f, bo = 0.f;
        if (!Wn_t) { wo0 = W_out[lane]; wo1 = W_out[64+lane]; bo = b_out[0]; }
#pragma unroll
        for (int i = 0; i < 4; i++) {
            int r = wave*4 + i;
            int gr = row0 + r;
            float mk = mask[gr > NROWS-1 ? NROWS-1 : gr];
            float x0 = xs[r*132 + lane], x1 = xs[r*132 + 64 + lane];
            float sm = x0 + x1, sq = x0*x0 + x1*x1;
#pragma unroll
            for (int m = 1; m < 64; m <<= 1) {
                sm += __shfl_xor(sm, m, 64);
                sq += __shfl_xor(sq, m, 64);
            }
            float mu = sm*(1.0f/H);
            float rs = rsqrtf(sq*(1.0f/H) - mu*mu + LN_EPS);
            float v0 = mk*(g0*(x0-mu)*rs + b0), v1 = mk*(g1*(x1-mu)*rs + b1);
            yz[r*136 + lane] = __float2bfloat16(v0);
            yz[r*136 + 64 + lane] = __float2bfloat16(v1);
            if (gr < NROWS) {
                hv[(size_t)gr*128 + lane] = v0;
                hv[(size_t)gr*128 + 64 + lane] = v1;
            }
            if (!Wn_t) {
                float o = v0*wo0 + v1*wo1;
#pragma unroll
                for (int m = 1; m < 64; m <<= 1) o += __shfl_xor(o, m, 64);
                if (lane == 0 && gr < NROWS) out[gr] = o + bo;
            }
        }
    }
    __syncthreads();

    // next-layer node proj: 33 tiles over 8 waves (5 each, guard)
    if (Wn_t) {
        __hip_bfloat16* Pbw = (__hip_bfloat16*)P;
        for (int ntl = 0; ntl < 5; ntl++) {
            int nt = wave*5 + ntl;
            if (nt >= 33) break;
            int cc = nt*16 + lm;
            f4v a0 = {0.f,0.f,0.f,0.f}, a1 = a0;
#pragma unroll
            for (int ks = 0; ks < 4; ks++) {
                s8v wf = *(const s8v*)&Wn_t[(size_t)(nt*16+lm)*128 + ks*32 + lq*8];
                s8v f0 = *(const s8v*)&yz[lm*136 + ks*32 + lq*8];
                s8v f1 = *(const s8v*)&yz[(16+lm)*136 + ks*32 + lq*8];
                a0 = __builtin_amdgcn_mfma_f32_16x16x32_bf16(f0, wf, a0, 0,0,0);
                a1 = __builtin_amdgcn_mfma_f32_16x16x32_bf16(f1, wf, a1, 0,0,0);
            }
#pragma unroll
            for (int mt = 0; mt < 2; mt++) {
                f4v* ap = mt ? &a1 : &a0;
#pragma unroll
                for (int r = 0; r < 4; r++) {
                    int rr = row0 + mt*16 + lq*4 + r;
                    if (rr < NROWS) {
                        float av = (*ap)[r];
                        if (cc < 128)
                            P[(size_t)rr*P_F32_STRIDE + cc] = av;
                        else if (cc < 256)
                            Pbw[(size_t)rr*P_BF16_STRIDE + 640 + (cc-128)] = __float2bfloat16(av);
                        else if (cc < 272) {
                            if (cc < 260) qg_buf[rr*4 + (cc-256)] = av;
                        } else
                            PKV[(size_t)rr*256 + (cc-272)] = __float2bfloat16(av);
                    }
                }
            }
        }
    }
}

// ---------------------------------------------------------------- launch
extern "C" void kernel_launch(void* const* d_in, const int* in_sizes, int n_in,
                              void* d_out, int out_size, void* d_ws, size_t ws_size,
                              hipStream_t stream)
{
    const float* X      = (const float*)d_in[0];
    const float* V      = (const float*)d_in[1];
    const float* mask   = (const float*)d_in[2];
    const float* W_v    = (const float*)d_in[3];
    const float* b_v    = (const float*)d_in[4];
    const float* W_e    = (const float*)d_in[5];
    const float* b_e    = (const float*)d_in[6];
    const float* W_edge = (const float*)d_in[7];
    const float* ln_e_g = (const float*)d_in[8];
    const float* ln_e_b = (const float*)d_in[9];
    const float* Wq     = (const float*)d_in[10];
    const float* Wk     = (const float*)d_in[11];
    const float* Wv_a   = (const float*)d_in[12];
    const float* Wo     = (const float*)d_in[13];
    const float* ln1g   = (const float*)d_in[14];
    const float* ln1b   = (const float*)d_in[15];
    const float* ln2g   = (const float*)d_in[16];
    const float* ln2b   = (const float*)d_in[17];
    const float* Wf1    = (const float*)d_in[18];
    const float* bf1    = (const float*)d_in[19];
    const float* Wf2    = (const float*)d_in[20];
    const float* bf2    = (const float*)d_in[21];
    const float* W_out  = (const float*)d_in[22];
    const float* b_out  = (const float*)d_in[23];
    float* out = (float*)d_out;

    // workspace layout
    char* ws = (char*)d_ws;
    int*            E_idx    = (int*)ws;                                   //   720000
    float*          D_nb     = (float*)(ws + 720000);                      //   720000
    float*          hv       = (float*)(ws + 47520000);                    //  3072000
    float*          bias_kv  = (float*)(ws + 50592000);                    //     4096
    float*          Wkv_f    = (float*)(ws + 50596096);                    //   524288
    __hip_bfloat16* Wn_t     = (__hip_bfloat16*)(ws + 51120384);           //   540672 used
    __hip_bfloat16* WoU_t    = (__hip_bfloat16*)(ws + 52037888);           //   294912 used
    __hip_bfloat16* Wf1_t    = (__hip_bfloat16*)(ws + 52693248);           //   524288
    __hip_bfloat16* Wf2_t    = (__hip_bfloat16*)(ws + 53217536);           //   524288
    __hip_bfloat16* Wv_t     = (__hip_bfloat16*)(ws + 53741824);           //   262144
    __hip_bfloat16* W_edge_t = (__hip_bfloat16*)(ws + 54003968);           //     8192
    __hip_bfloat16* PKV      = (__hip_bfloat16*)(ws + 54012160);           //  3072000
    float*          P        = (float*)(ws + 57084160);                    //  9216000
    float*          EMS      = (float*)(ws + 66300160);                    //  1440000
    float*          M_buf    = (float*)(ws + 67740160);                    //    65536
    float*          vg_buf   = (float*)(ws + 67805696);                    //     2048
    float*          qg_buf   = (float*)(ws + 67807744);                    //    96000

    topk_kernel<<<NROWS, 256, 0, stream>>>(X, mask, E_idx, D_nb);
    wprep_edge_kernel<<<16, 256, 0, stream>>>(W_edge, W_edge_t);
    edge_kernel<<<NROWS/2, 256, 0, stream>>>(E_idx, D_nb, W_edge_t, EMS);
    wprep_kv_kernel<<<1024, 128, 0, stream>>>(W_e, b_e, Wk, Wv_a, Wkv_f, bias_kv);
    wprep_m_kernel<<<512, 128, 0, stream>>>(Wkv_f, W_edge, ln_e_g, M_buf, vg_buf);
    wprep_q2_kernel<<<512, 128, 0, stream>>>(Wq, M_buf, vg_buf, Wn_t);
    wprep_op2_kernel<<<2048, 128, 0, stream>>>(Wo, Wkv_f, W_edge, ln_e_g, ln_e_b, WoU_t);
    wprep_op_kernel<<<608, 128, 0, stream>>>(Wo, WoU_t);
    wprep_post_kernel<<<2816, 256, 0, stream>>>(Wf1, Wf2, Wq, Wk, Wv_a,
                                                Wf1_t, Wf2_t, Wn_t);
    wprep_v_kernel<<<512, 256, 0, stream>>>(W_v, Wv_t);
    hv_init_kernel<<<(NROWS+31)/32, 512, 0, stream>>>(V, Wv_t, b_v, hv, Wn_t, P, PKV, qg_buf);

    for (int l = 0; l < 4; l++) {
        attn_kernel<<<NROWS/2, 256, 0, stream>>>(
            bias_kv + l*256 + 128, P, PKV, E_idx, D_nb, EMS, qg_buf, mask);
        post_kernel<<<(NROWS+31)/32, 512, 0, stream>>>(
            hv, P, PKV, qg_buf, mask, WoU_t + (size_t)l*128*UK,
            ln1g + l*H, ln1b + l*H, ln2g + l*H, ln2b + l*H,
            Wf1_t + (size_t)l*65536, bf1 + l*FFH,
            Wf2_t + (size_t)l*65536, bf2 + l*H,
            (l < 3) ? (Wn_t + (size_t)(l+1)*WNT_STRIDE) : (const __hip_bfloat16*)nullptr,
            W_out, b_out, out);
    }
}

// Round 16
// 392.061 us; speedup vs baseline: 1.1495x; 1.0140x over previous
//
#include <hip/hip_runtime.h>
#include <hip/hip_bf16.h>
#include <math.h>

#define NB 4
#define NN 1500
#define KNB 30
#define H 128
#define NHEADS 4
#define FFH 512
#define NODE_FEAT 1024
#define NROWS (NB*NN)
#define LN_EPS 1e-6f

// P layout per node: 1536 B = [Q f32 x128 | (bytes 1280..1535) Q'' bf16 x128];
// attn overwrites bf16 cols 0..287 with U = [Phibar(h*32+f) x128 | sbar x4 |
// ss x4 | pad x8 | vpart x128 | pad x16].
#define P_F32_STRIDE 384
#define P_BF16_STRIDE 768
#define UK 288

// Wn_t per-layer: 528 rows x 128 k (bf16). rows 0-127 Q, 128-255 Q'' (WQ2),
// 256-259 wqg, 260-271 zero pad, 272-399 Kbot, 400-527 Vbot.
#define WNT_STRIDE 67584

typedef __attribute__((ext_vector_type(8))) short s8v;   // 8 bf16 = 4 VGPRs (MFMA A/B frag)
typedef __attribute__((ext_vector_type(4))) float f4v;   // MFMA C/D frag

__device__ __forceinline__ float bf_lo(unsigned u){ union{unsigned i; float f;} v; v.i = u<<16; return v.f; }
__device__ __forceinline__ float bf_hi(unsigned u){ union{unsigned i; float f;} v; v.i = u & 0xffff0000u; return v.f; }

// ---------------------------------------------------------------- topk (radix select)
__device__ __forceinline__ void find_bucket30(
    const unsigned* hist, int base0, int t, int lane, int wave,
    int* wsum, int* res)
{
    int h[16], s = 0;
    const uint4* hp = (const uint4*)&hist[(t & 127) * 16];
    int sh = (t >> 7) << 4;
    uint4 w[4] = {hp[0], hp[1], hp[2], hp[3]};
#pragma unroll
    for (int i = 0; i < 4; i++) {
        h[i*4+0] = (w[i].x >> sh) & 0xffff;
        h[i*4+1] = (w[i].y >> sh) & 0xffff;
        h[i*4+2] = (w[i].z >> sh) & 0xffff;
        h[i*4+3] = (w[i].w >> sh) & 0xffff;
        s += h[i*4+0] + h[i*4+1] + h[i*4+2] + h[i*4+3];
    }
    int inc = s;
#pragma unroll
    for (int off = 1; off < 64; off <<= 1) {
        int o = __shfl_up(inc, off, 64);
        if (lane >= off) inc += o;
    }
    if (lane == 63) wsum[wave] = inc;
    __syncthreads();
    int base = base0 + inc - s;
    for (int w2 = 0; w2 < wave; w2++) base += wsum[w2];
    if (base < KNB && base + s >= KNB) {
        int running = base;
#pragma unroll
        for (int i = 0; i < 16; i++) {
            if (running < KNB && running + h[i] >= KNB) { res[0] = (t<<4)|i; res[1] = running; break; }
            running += h[i];
        }
    }
    __syncthreads();
}

__global__ __launch_bounds__(256) void topk_kernel(
    const float* __restrict__ X, const float* __restrict__ mask,
    int* __restrict__ E_idx, float* __restrict__ D_nb)
{
    int row = blockIdx.x;            // b*NN + i
    int b = row / NN;
    int t = threadIdx.x;
    int wave = t >> 6, lane = t & 63;
    __shared__ float d_adj[NN];
    __shared__ unsigned hist[2048];
    __shared__ float redw[4];
    __shared__ int   wsum[4];
    __shared__ int   res[2];
    __shared__ int   cand[64];
    __shared__ int   ncand;

    float xi0 = X[row*3+0], xi1 = X[row*3+1], xi2 = X[row*3+2];
    float mi = mask[row];

    float dr[6], m2r[6];
    float lmax = -1e30f;
#pragma unroll
    for (int q = 0; q < 6; q++) {
        int j = t + q*256;
        float d = 0.f, m2 = 0.f;
        if (j < NN) {
            float dx = xi0 - X[(b*NN+j)*3+0];
            float dy = xi1 - X[(b*NN+j)*3+1];
            float dz = xi2 - X[(b*NN+j)*3+2];
            d  = sqrtf(dx*dx + dy*dy + dz*dz + 1e-6f);
            m2 = mi * mask[b*NN+j];
            lmax = fmaxf(lmax, m2*d);
        }
        dr[q] = d; m2r[q] = m2;
    }
    for (int q = t; q < 2048; q += 256) hist[q] = 0;
#pragma unroll
    for (int off = 32; off > 0; off >>= 1)
        lmax = fmaxf(lmax, __shfl_xor(lmax, off, 64));
    if (lane == 0) redw[wave] = lmax;
    if (t == 0) ncand = 0;
    __syncthreads();
    float rowmax = fmaxf(fmaxf(redw[0], redw[1]), fmaxf(redw[2], redw[3]));

    unsigned kreg[6];
#pragma unroll
    for (int q = 0; q < 6; q++) {
        int j = t + q*256;
        if (j < NN) {
            float dv = m2r[q]*dr[q] + (1.0f - m2r[q])*rowmax;   // >= 0
            d_adj[j] = dv;
            unsigned key = __float_as_uint(dv);
            kreg[q] = key;
            unsigned bkt = key >> 20;
            atomicAdd(&hist[bkt & 2047], 1u << ((bkt >> 11) << 4));
        } else kreg[q] = 0xFFFFFFFFu;
    }
    __syncthreads();

    find_bucket30(hist, 0, t, lane, wave, wsum, res);
    int B1 = res[0], nb1 = res[1];

    for (int q = t; q < 2048; q += 256) hist[q] = 0;
    __syncthreads();
#pragma unroll
    for (int q = 0; q < 6; q++) {
        if ((kreg[q] >> 20) == (unsigned)B1) {
            unsigned bkt = (kreg[q] >> 8) & 0xFFF;
            atomicAdd(&hist[bkt & 2047], 1u << ((bkt >> 11) << 4));
        }
    }
    __syncthreads();

    find_bucket30(hist, nb1, t, lane, wave, wsum, res);
    unsigned Bfull = ((unsigned)B1 << 12) | (unsigned)res[0];

#pragma unroll
    for (int q = 0; q < 6; q++) {
        if ((kreg[q] >> 8) <= Bfull) {
            int slot = atomicAdd(&ncand, 1);
            if (slot < 64) cand[slot] = t + q*256;
        }
    }
    __syncthreads();

    if (wave == 0) {
        int nc = min(ncand, 64);
        if (lane < nc) {
            int j = cand[lane];
            float v = d_adj[j];
            int rank = 0;
            for (int m = 0; m < nc; m++) {
                int jm = cand[m];
                float vm = d_adj[jm];
                rank += (vm < v || (vm == v && jm < j)) ? 1 : 0;
            }
            if (rank < KNB) {
                E_idx[row*KNB + rank] = j;
                D_nb[row*KNB + rank]  = v;
            }
        }
    }
}

// ---------------------------------------------------------------- consolidated cast/transpose prep (launch-count reduction):
// blocks [0,16):    W_edge transpose+cast -> W_edge_t[n][k] bf16 (128x32)
// blocks [16,528):  W_v transpose+cast -> Wv_t[n][k] bf16
// blocks [528,3344): FF weights + Wn_t Q/Kbot/Vbot parts
// blocks [3344,3856): fold W_e into per-layer edge K/V (fp32) + bias (2 cols/block)
__global__ __launch_bounds__(256) void wprep_cast_kernel(
    const float* __restrict__ W_edge, __hip_bfloat16* __restrict__ W_edge_t,
    const float* __restrict__ W_v, __hip_bfloat16* __restrict__ Wv_t,
    const float* __restrict__ Wf1, const float* __restrict__ Wf2,
    const float* __restrict__ Wq, const float* __restrict__ Wk,
    const float* __restrict__ Wv_a,
    __hip_bfloat16* __restrict__ Wf1_t, __hip_bfloat16* __restrict__ Wf2_t,
    __hip_bfloat16* __restrict__ Wn_t,
    const float* __restrict__ W_e, const float* __restrict__ b_e,
    float* __restrict__ Wkv_f, float* __restrict__ bias_kv)
{
    int blk = blockIdx.x;
    int t = threadIdx.x;
    if (blk < 16) {
        int tid = blk*256 + t;                // 4096
        int n = tid >> 5, k = tid & 31;
        W_edge_t[tid] = __float2bfloat16(W_edge[k*H + n]);
    } else if (blk < 528) {
        int tid = (blk-16)*256 + t;           // 131072
        int n = tid & 127, k = tid >> 7;
        Wv_t[(size_t)n*NODE_FEAT + k] = __float2bfloat16(W_v[k*H + n]);
    } else if (blk < 3344) {
        int id = (blk-528)*256 + t;           // < 720896
        int l = id / 180224;
        int r = id - l*180224;
        float v; __hip_bfloat16* dst;
        if (r < 65536) {
            int n = r >> 7, k = r & 127;
            v = Wf1[(size_t)l*65536 + k*512 + n];
            dst = Wf1_t + (size_t)l*65536 + r;
        } else if (r < 131072) {
            int rr = r - 65536;
            int n = rr >> 9, k = rr & 511;
            v = Wf2[(size_t)l*65536 + k*128 + n];
            dst = Wf2_t + (size_t)l*65536 + rr;
        } else if (r < 147456) {
            int rr = r - 131072;              // Q block: rows 0..127
            int n = rr >> 7, k = rr & 127;
            v = Wq[(size_t)l*16384 + k*128 + n];
            dst = Wn_t + (size_t)l*WNT_STRIDE + rr;
        } else {
            int rr = r - 147456;              // Kbot/Vbot -> rows 272..527
            int n = rr >> 7, k = rr & 127;
            v = (n < 128) ? Wk[(size_t)l*32768 + (128+k)*128 + n]
                          : Wv_a[(size_t)l*32768 + (128+k)*128 + (n-128)];
            dst = Wn_t + (size_t)l*WNT_STRIDE + 272*H + rr;
        }
        *dst = __float2bfloat16(v);
    } else {
        // kv fold: 2 cols per block, half = t>>7 (128 threads each)
        int bb = blk - 3344;                  // 0..511
        int l = bb >> 7;
        int half = t >> 7, t2 = t & 127;      // t2 = e
        int n = (bb & 127)*2 + half;          // 0..255
        int col = n & 127;
        const float* W = (n < 128) ? (Wk + l*2*H*H) : (Wv_a + l*2*H*H);
        __shared__ float wcol[2][128];
        wcol[half][t2] = W[t2*H + col];       // rows 0..127 = h_E block
        __syncthreads();
        float a = 0.f;
        const float* wc = wcol[half];
        for (int c = 0; c < H; c += 4) {
            float4 we = *(const float4*)&W_e[t2*H + c];
            a += we.x*wc[c] + we.y*wc[c+1] + we.z*wc[c+2] + we.w*wc[c+3];
        }
        Wkv_f[(size_t)(l*256 + n)*H + t2] = a;   // Wek/Wev [e=t2][col=n], stored [n][e]
        if (t2 == 0) {
            float bsum = 0.f;
            for (int c = 0; c < H; c++) bsum += b_e[c]*wc[c];
            bias_kv[l*256 + n] = bsum;
        }
    }
}

// ---------------------------------------------------------------- edge stats -> per-edge (rs, mu*rs) only, MFMA
__global__ __launch_bounds__(256) void edge_kernel(
    const int* __restrict__ E_idx, const float* __restrict__ D_nb,
    const __hip_bfloat16* __restrict__ W_edge_t, float* __restrict__ EMS)
{
    int g0 = blockIdx.x * 2;
    int t = threadIdx.x;
    int wave = t >> 6, lane = t & 63, lm = lane & 15, lq = lane >> 4;

    int row = wave*16 + lm;
    int rr = row < 60 ? row : 59;
    int node = g0 + (rr >= KNB ? 1 : 0);
    int e = node*KNB + (rr >= KNB ? rr - KNB : rr);
    float drel = (float)(E_idx[e] - (node % NN));
    float dnb  = D_nb[e];

    const float FR[8] = {1.f, 0.31622776601683794f, 0.1f, 0.031622776601683794f,
                         0.01f, 0.0031622776601683794f, 0.001f, 0.00031622776601683794f};
    union { s8v v; __hip_bfloat16 h[8]; } af;
    if (lq == 0) {
#pragma unroll
        for (int j = 0; j < 8; j++) af.h[j] = __float2bfloat16(cosf(drel*FR[j]));
    } else if (lq == 1) {
#pragma unroll
        for (int j = 0; j < 8; j++) af.h[j] = __float2bfloat16(sinf(drel*FR[j]));
    } else {
        int f0 = (lq-2)*8;
#pragma unroll
        for (int j = 0; j < 8; j++) {
            float mu = (20.0f/15.0f) * (float)(f0+j);
            float z = (dnb - mu) * 0.8f;
            af.h[j] = __float2bfloat16(expf(-z*z));
        }
    }

    f4v acc[8];
#pragma unroll
    for (int nt = 0; nt < 8; nt++) {
        s8v bf = *(const s8v*)&W_edge_t[(nt*16+lm)*32 + lq*8];
        f4v z = {0.f,0.f,0.f,0.f};
        acc[nt] = __builtin_amdgcn_mfma_f32_16x16x32_bf16(af.v, bf, z, 0,0,0);
    }

#pragma unroll
    for (int r = 0; r < 4; r++) {
        float sm = 0.f, sq = 0.f;
#pragma unroll
        for (int nt = 0; nt < 8; nt++) { float x = acc[nt][r]; sm += x; sq += x*x; }
#pragma unroll
        for (int m = 1; m < 16; m <<= 1) {
            sm += __shfl_xor(sm, m, 64);
            sq += __shfl_xor(sq, m, 64);
        }
        float mu = sm * (1.0f/H);
        float rs = rsqrtf(sq*(1.0f/H) - mu*mu + LN_EPS);
        int erow = wave*16 + lq*4 + r;
        if (lm == 0 && erow < 60) {
            EMS[(g0*KNB + erow)*2]     = rs;
            EMS[(g0*KNB + erow)*2 + 1] = mu*rs;
        }
    }
}

// ---------------------------------------------------------------- consolidated fold kernels (all depend only on Wkv_f):
// blocks [0,512):    M[l][n][f], vg[l][n]
// blocks [512,2560): Ebar fold (A_h, -u_h, w_h) -> WoU_t k<136
// blocks [2560,3168): WoU tail k in [136,288)
__global__ __launch_bounds__(128) void wprep_mop_kernel(
    const float* __restrict__ Wkv_f, const float* __restrict__ W_edge,
    const float* __restrict__ ln_e_g, const float* __restrict__ ln_e_b,
    const float* __restrict__ Wo,
    float* __restrict__ M_buf, float* __restrict__ vg_buf,
    __hip_bfloat16* __restrict__ WoU_t)
{
    int blk = blockIdx.x;
    if (blk < 512) {
        int l = blk >> 7;
        int n = blk & 127;
        int t = threadIdx.x;
        __shared__ float wg_s[128];
        wg_s[t] = Wkv_f[(size_t)(l*256 + n)*H + t] * ln_e_g[t];
        __syncthreads();
        if (t < 32) {
            float a = 0.f;
            for (int e = 0; e < 128; e++) a += wg_s[e] * W_edge[t*H + e];
            M_buf[((size_t)(l*128 + n))*32 + t] = a;
        } else if (t == 32) {
            float a = 0.f;
            for (int e = 0; e < 128; e++) a += wg_s[e];
            vg_buf[l*128 + n] = a;
        }
    } else if (blk < 2560) {
        int bb = blk - 512;
        int l = bb >> 9;
        int hn = bb & 511;
        int h = hn >> 7, n = hn & 127;
        int e = threadIdx.x;
        __shared__ float tg[128], tb[128];
        float tmp = 0.f;
        const float* wo = Wo + (size_t)l*16384 + (h*32)*128 + n;
        for (int d = 0; d < 32; d++)
            tmp += Wkv_f[(size_t)(l*256 + 128 + h*32 + d)*H + e] * wo[d*128];
        tg[e] = ln_e_g[e] * tmp;
        tb[e] = ln_e_b[e] * tmp;
        __syncthreads();
        if (e < 32) {
            float a = 0.f;
            for (int ee = 0; ee < 128; ee++) a += W_edge[e*H + ee] * tg[ee];
            WoU_t[((size_t)l*128 + n)*UK + h*32 + e] = __float2bfloat16(a);
        } else if (e == 32) {
            float a = 0.f, b = 0.f;
            for (int ee = 0; ee < 128; ee++) { a += tg[ee]; b += tb[ee]; }
            WoU_t[((size_t)l*128 + n)*UK + 128 + h] = __float2bfloat16(-a);
            WoU_t[((size_t)l*128 + n)*UK + 132 + h] = __float2bfloat16(b);
        }
    } else {
        int bb = blk - 2560;
        int l = bb / 152;
        int kk = 136 + (bb % 152);
        int n = threadIdx.x;
        float v = 0.f;
        if (kk >= 144 && kk < 272) v = Wo[(size_t)l*16384 + (kk-144)*128 + n];
        WoU_t[((size_t)l*128 + n)*UK + kk] = __float2bfloat16(v);
    }
}

// ---------------------------------------------------------------- rank-32 fold part 2:
// WQ2[l][c][h*32+f] = sum_d Wq[c][h32+d]*M[h32+d][f] -> Wn_t rows 128..255
// wqg[l][c][h]     = sum_d Wq[c][h32+d]*vg[h32+d]    -> Wn_t rows 256..259; 260..271 zero
__global__ __launch_bounds__(128) void wprep_q2_kernel(
    const float* __restrict__ Wq, const float* __restrict__ M_buf,
    const float* __restrict__ vg_buf, __hip_bfloat16* __restrict__ Wn_t)
{
    int l = blockIdx.x >> 7;
    int c = blockIdx.x & 127;
    int t = threadIdx.x;            // h*32+f
    int h = t >> 5, f = t & 31;
    __shared__ float wq_s[128];
    wq_s[t] = Wq[(size_t)l*16384 + c*128 + t];
    __syncthreads();
    float a = 0.f;
#pragma unroll
    for (int d = 0; d < 32; d++)
        a += wq_s[h*32 + d] * M_buf[((size_t)(l*128 + h*32 + d))*32 + f];
    Wn_t[(size_t)l*WNT_STRIDE + (128 + t)*H + c] = __float2bfloat16(a);
    if (t < 4) {
        float b = 0.f;
        for (int d = 0; d < 32; d++)
            b += wq_s[t*32 + d] * vg_buf[l*128 + t*32 + d];
        Wn_t[(size_t)l*WNT_STRIDE + (256 + t)*H + c] = __float2bfloat16(b);
    }
    if (t < 12) Wn_t[(size_t)l*WNT_STRIDE + (260 + t)*H + c] = __float2bfloat16(0.f);
}

// ---------------------------------------------------------------- h_V = V @ W_v + b_v  (MFMA)
// + fused layer-0 node projections (33 tiles: Q | Q'' | qg | Kbot | Vbot)
__global__ __launch_bounds__(512) void hv_init_kernel(
    const float* __restrict__ V, const __hip_bfloat16* __restrict__ Wv_t,
    const float* __restrict__ b_v, float* __restrict__ hv,
    const __hip_bfloat16* __restrict__ Wn_t, float* __restrict__ P,
    __hip_bfloat16* __restrict__ PKV, float* __restrict__ qg_buf)
{
    int row0 = blockIdx.x * 32;
    int t = threadIdx.x;
    int wave = t >> 6, lane = t & 63, lm = lane & 15, lq = lane >> 4;
    __shared__ __hip_bfloat16 Vs[32*1032];   // pitch 1032 (2-way bank alias only)
    __shared__ __hip_bfloat16 zs[32*136];

    for (int q = t; q < 8192; q += 512) {
        int r = q >> 8, c4 = (q & 255) * 4;
        int gr = row0 + r; if (gr > NROWS-1) gr = NROWS-1;
        float4 v4 = *(const float4*)&V[(size_t)gr*NODE_FEAT + c4];
        union { ushort u[4]; uint2 w; } pk;
        pk.u[0] = __bfloat16_as_ushort(__float2bfloat16(v4.x));
        pk.u[1] = __bfloat16_as_ushort(__float2bfloat16(v4.y));
        pk.u[2] = __bfloat16_as_ushort(__float2bfloat16(v4.z));
        pk.u[3] = __bfloat16_as_ushort(__float2bfloat16(v4.w));
        *(uint2*)&Vs[r*1032 + c4] = pk.w;
    }
    __syncthreads();

    // h_V GEMM: wave w -> n-tile w; weight frag reused across m-tiles 0/1
    {
        int cc = wave*16 + lm;
        float b = b_v[cc];
        f4v a0 = {0.f,0.f,0.f,0.f}, a1 = a0;
        for (int ks = 0; ks < 32; ks++) {
            s8v wf = *(const s8v*)&Wv_t[(size_t)(wave*16+lm)*NODE_FEAT + ks*32 + lq*8];
            s8v f0 = *(const s8v*)&Vs[lm*1032 + ks*32 + lq*8];
            s8v f1 = *(const s8v*)&Vs[(16+lm)*1032 + ks*32 + lq*8];
            a0 = __builtin_amdgcn_mfma_f32_16x16x32_bf16(f0, wf, a0, 0,0,0);
            a1 = __builtin_amdgcn_mfma_f32_16x16x32_bf16(f1, wf, a1, 0,0,0);
        }
#pragma unroll
        for (int r = 0; r < 4; r++) {
            int rr0 = lq*4 + r, rr1 = 16 + lq*4 + r;
            int g0 = row0 + rr0, g1 = row0 + rr1;
            float v0 = a0[r] + b, v1 = a1[r] + b;
            if (g0 < NROWS) hv[(size_t)g0*H + cc] = v0;
            if (g1 < NROWS) hv[(size_t)g1*H + cc] = v1;
            zs[rr0*136+cc] = __float2bfloat16(v0);
            zs[rr1*136+cc] = __float2bfloat16(v1);
        }
    }
    __syncthreads();

    // layer-0 node projections: 33 tiles over 8 waves (5 each, guard)
    __hip_bfloat16* Pb = (__hip_bfloat16*)P;
    for (int ntl = 0; ntl < 5; ntl++) {
        int nt = wave*5 + ntl;
        if (nt >= 33) break;
        int cc = nt*16 + lm;
        f4v a0 = {0.f,0.f,0.f,0.f}, a1 = a0;
#pragma unroll
        for (int ks = 0; ks < 4; ks++) {
            s8v wf = *(const s8v*)&Wn_t[(size_t)(nt*16+lm)*H + ks*32 + lq*8];
            s8v f0 = *(const s8v*)&zs[lm*136 + ks*32 + lq*8];
            s8v f1 = *(const s8v*)&zs[(16+lm)*136 + ks*32 + lq*8];
            a0 = __builtin_amdgcn_mfma_f32_16x16x32_bf16(f0, wf, a0, 0,0,0);
            a1 = __builtin_amdgcn_mfma_f32_16x16x32_bf16(f1, wf, a1, 0,0,0);
        }
#pragma unroll
        for (int mt = 0; mt < 2; mt++) {
            f4v* ap = mt ? &a1 : &a0;
#pragma unroll
            for (int r = 0; r < 4; r++) {
                int rr = row0 + mt*16 + lq*4 + r;
                if (rr < NROWS) {
                    float av = (*ap)[r];
                    if (cc < 128)
                        P[(size_t)rr*P_F32_STRIDE + cc] = av;
                    else if (cc < 256)
                        Pb[(size_t)rr*P_BF16_STRIDE + 640 + (cc-128)] = __float2bfloat16(av);
                    else if (cc < 272) {
                        if (cc < 260) qg_buf[rr*4 + (cc-256)] = av;
                    } else
                        PKV[(size_t)rr*256 + (cc-272)] = __float2bfloat16(av);
                }
            }
        }
    }
}

// ---------------------------------------------------------------- attention: 2 nodes/block, 5-phase (proven shape).
// Rank-32 logits AND rank-32 Ebar: no E_ln anywhere. Phi recomputed with
// fast-math trig. U = [Phibar x128 | sbar x4 | ss x4 | 0 x8 | vpart x128 | 0 x16].
__global__ __launch_bounds__(256) void attn_kernel(
    const float* __restrict__ biasv,
    float* __restrict__ P, const __hip_bfloat16* __restrict__ PKV,
    const int* __restrict__ E_idx, const float* __restrict__ D_nb,
    const float* __restrict__ EMS, const float* __restrict__ qg_buf,
    const float* __restrict__ mask)
{
    int g0 = blockIdx.x * 2;
    int t = threadIdx.x;
    int wave = t >> 6, lane = t & 63, lm = lane & 15, lq = lane >> 4;
    __shared__ __hip_bfloat16 Ps[60*40];     // Phi rows (32 used), 4800 B
    __shared__ __hip_bfloat16 Qps[2*136];    // Q'' bf16 (128 used)
    __shared__ float Qs[2*128];              // Q f32
    __shared__ float att_s[2*128];           // [node][h*32+k]
    __shared__ float ssum[8];                // [node][h]
    __shared__ float mv_s[60];
    __shared__ float rs_s[60], murs_s[60];
    __shared__ float qgs[8];
    __shared__ int   nbr[60];

    const __hip_bfloat16* Pb = (const __hip_bfloat16*)P;
    if (t < 32) {
        int node = t >> 4, c8 = (t & 15)*8;
        *(s8v*)&Qps[node*136 + c8] = *(const s8v*)&Pb[(size_t)(g0+node)*P_BF16_STRIDE + 640 + c8];
    }
    {
        int node = t >> 7, c = t & 127;
        Qs[t] = P[(size_t)(g0+node)*P_F32_STRIDE + c];
    }
    if (t < 60) {
        int gn = g0 + t/30;
        int b = gn / NN;
        int idx = E_idx[gn*KNB + (t%30)];
        nbr[t]  = b*NN + idx;
        mv_s[t] = mask[gn] * mask[b*NN + idx];
        float2 em = ((const float2*)EMS)[g0*KNB + t];
        rs_s[t] = em.x; murs_s[t] = em.y;
    }
    if (t < 8) qgs[t] = qg_buf[(g0 + (t>>2))*4 + (t&3)];
    // Phi recompute: 4 threads per edge (seg = 8-dim slice), fast-math trig
    if (t < 240) {
        int r = t >> 2, seg = t & 3;
        int gn = g0 + r/30;
        int e = gn*KNB + (r%30);
        float drel = (float)(E_idx[e] - (gn % NN));
        float dnb  = D_nb[e];
        const float FR[8] = {1.f, 0.31622776601683794f, 0.1f, 0.031622776601683794f,
                             0.01f, 0.0031622776601683794f, 0.001f, 0.00031622776601683794f};
        union { s8v v; __hip_bfloat16 h[8]; } pf;
        if (seg == 0) {
#pragma unroll
            for (int j = 0; j < 8; j++) pf.h[j] = __float2bfloat16(__cosf(drel*FR[j]));
        } else if (seg == 1) {
#pragma unroll
            for (int j = 0; j < 8; j++) pf.h[j] = __float2bfloat16(__sinf(drel*FR[j]));
        } else {
            int f0 = (seg-2)*8;
#pragma unroll
            for (int j = 0; j < 8; j++) {
                float mu = (20.0f/15.0f) * (float)(f0+j);
                float z = (dnb - mu) * 0.8f;
                pf.h[j] = __float2bfloat16(__expf(-z*z));
            }
        }
        *(s8v*)&Ps[r*40 + seg*8] = pf.v;
    }
    __syncthreads();

    // logits: rank-32 edge dot + Kbot gather dot
    if (t < 240) {
        int node = t/120, tt = t%120, h = tt/30, kk = tt%30;
        int r = node*30 + kk;
        const uint4* pp = (const uint4*)&Ps[r*40];
        const uint4* qp = (const uint4*)&Qps[node*136 + h*32];
        float a = 0.f;
#pragma unroll
        for (int j = 0; j < 4; j++) {
            uint4 e4 = pp[j], q4 = qp[j];
            a += bf_lo(e4.x)*bf_lo(q4.x) + bf_hi(e4.x)*bf_hi(q4.x);
            a += bf_lo(e4.y)*bf_lo(q4.y) + bf_hi(e4.y)*bf_hi(q4.y);
            a += bf_lo(e4.z)*bf_lo(q4.z) + bf_hi(e4.z)*bf_hi(q4.z);
            a += bf_lo(e4.w)*bf_lo(q4.w) + bf_hi(e4.w)*bf_hi(q4.w);
        }
        a = rs_s[r]*a - murs_s[r]*qgs[node*4 + h];
        const uint4* kb = (const uint4*)(PKV + (size_t)nbr[r]*256 + h*32);
        const float* q = &Qs[node*128 + h*32];
#pragma unroll
        for (int j = 0; j < 4; j++) {
            uint4 u = kb[j];
            const float* q8 = q + j*8;
            a += q8[0]*bf_lo(u.x) + q8[1]*bf_hi(u.x)
               + q8[2]*bf_lo(u.y) + q8[3]*bf_hi(u.y)
               + q8[4]*bf_lo(u.z) + q8[5]*bf_hi(u.z)
               + q8[6]*bf_lo(u.w) + q8[7]*bf_hi(u.w);
        }
        att_s[node*128 + h*32 + kk] =
            (mv_s[r] > 0.f) ? a*0.17677669529663687f : -3.4028235e38f;
    }
    __syncthreads();

    // parallel softmax: wave w = node w (w<2), 16 lanes per head, 2 entries/lane
    if (wave < 2) {
        int node = wave, h = lq, j = lm;
        float* ap = &att_s[node*128 + h*32];
        const float* mp = &mv_s[node*30];
        float a0 = ap[j];
        float a1 = (j+16 < KNB) ? ap[j+16] : -3.4028235e38f;
        float mx = fmaxf(a0, a1);
#pragma unroll
        for (int m = 1; m < 16; m <<= 1) mx = fmaxf(mx, __shfl_xor(mx, m, 64));
        float e0 = __expf(a0 - mx);
        float e1 = (j+16 < KNB) ? __expf(a1 - mx) : 0.f;
        float s = e0 + e1;
#pragma unroll
        for (int m = 1; m < 16; m <<= 1) s += __shfl_xor(s, m, 64);
        float inv = 1.0f / s;
        float w0 = e0 * inv * mp[j];
        float w1 = (j+16 < KNB) ? e1 * inv * mp[j+16] : 0.f;
        ap[j] = w0;
        if (j+16 < KNB) ap[j+16] = w1;
        float ss = w0 + w1;
#pragma unroll
        for (int m = 1; m < 16; m <<= 1) ss += __shfl_xor(ss, m, 64);
        if (j == 0) ssum[node*4 + h] = ss;
    }
    __syncthreads();

    // U = [Phibar | sbar | ss | 0 | vpart | 0] bf16 over P node region
    {
        int node = t >> 7, c = t & 127, h = c >> 5, f = c & 31;
        __hip_bfloat16* Ub = (__hip_bfloat16*)P + (size_t)(g0+node)*P_BF16_STRIDE;
        const float* ap = &att_s[node*128];
        const int* nb = &nbr[node*30];
        const float* ah = ap + h*32;

        // vpart col c
        float u = ssum[node*4 + h] * biasv[c];
        for (int k = 0; k < KNB; k++)
            u += ah[k] * __bfloat162float(PKV[(size_t)nb[k]*256 + 128 + c]);
        Ub[144 + c] = __float2bfloat16(u);

        // Phibar element (h, f)
        float pb = 0.f;
        for (int k = 0; k < KNB; k++)
            pb += ah[k] * rs_s[node*30+k] * __bfloat162float(Ps[(node*30+k)*40 + f]);
        Ub[c] = __float2bfloat16(pb);

        if (c < 4) {                 // sbar_h, ss_h for h=c
            const float* ah2 = ap + c*32;
            float sb = 0.f;
            for (int k = 0; k < KNB; k++) sb += ah2[k] * murs_s[node*30+k];
            Ub[128 + c] = __float2bfloat16(sb);
            Ub[132 + c] = __float2bfloat16(ssum[node*4 + c]);
        }
        if (c < 8)  Ub[136 + c] = __float2bfloat16(0.f);
        if (c >= 8 && c < 24) Ub[264 + c] = __float2bfloat16(0.f);   // 272..287
    }
}

// ---------------------------------------------------------------- WoU(K=288) + LN1 + FF + LN2 (+ next-layer node proj | out), MFMA
__global__ __launch_bounds__(512) void post_kernel(
    float* __restrict__ hv, float* __restrict__ P,
    __hip_bfloat16* __restrict__ PKV, float* __restrict__ qg_buf,
    const float* __restrict__ mask,
    const __hip_bfloat16* __restrict__ WoU_t,
    const float* __restrict__ ln1g, const float* __restrict__ ln1b,
    const float* __restrict__ ln2g, const float* __restrict__ ln2b,
    const __hip_bfloat16* __restrict__ Wf1_t, const float* __restrict__ bf1,
    const __hip_bfloat16* __restrict__ Wf2_t, const float* __restrict__ bf2,
    const __hip_bfloat16* __restrict__ Wn_t,
    const float* __restrict__ W_out, const float* __restrict__ b_out,
    float* __restrict__ out)
{
    int row0 = blockIdx.x * 32;
    int t = threadIdx.x;
    int wave = t >> 6, lane = t & 63, lm = lane & 15, lq = lane >> 4;

    __shared__ __hip_bfloat16 AusT1[32*520]; // Aus (pitch 296); later t1=relu(FF1) (pitch 520)
    __shared__ float xs[32*132];             // fp32 working rows
    __shared__ __hip_bfloat16 yz[32*136];    // LN1 out, then LN2 out
    __hip_bfloat16* Aus = AusT1;
    __hip_bfloat16* t1  = AusT1;

    const __hip_bfloat16* Pbc = (const __hip_bfloat16*)P;
    for (int q = t; q < 1152; q += 512) {
        int r = q/36, c8 = (q%36)*8;
        int gr = row0 + r; if (gr > NROWS-1) gr = NROWS-1;
        *(s8v*)&Aus[r*296 + c8] = *(const s8v*)&Pbc[(size_t)gr*P_BF16_STRIDE + c8];
    }
    __syncthreads();

    // WoU: wave w -> n-tile w; K=288 (9 ks); weight frag reused across m-tiles 0/1
    {
        int cc = wave*16 + lm;
        f4v a0 = {0.f,0.f,0.f,0.f}, a1 = a0;
        for (int ks = 0; ks < 9; ks++) {
            s8v wf = *(const s8v*)&WoU_t[(size_t)(wave*16+lm)*UK + ks*32 + lq*8];
            s8v f0 = *(const s8v*)&Aus[lm*296 + ks*32 + lq*8];
            s8v f1 = *(const s8v*)&Aus[(16+lm)*296 + ks*32 + lq*8];
            a0 = __builtin_amdgcn_mfma_f32_16x16x32_bf16(f0, wf, a0, 0,0,0);
            a1 = __builtin_amdgcn_mfma_f32_16x16x32_bf16(f1, wf, a1, 0,0,0);
        }
#pragma unroll
        for (int r = 0; r < 4; r++) {
            int rr0 = lq*4 + r, rr1 = 16 + lq*4 + r;
            int g0 = row0 + rr0; if (g0 > NROWS-1) g0 = NROWS-1;
            int g1 = row0 + rr1; if (g1 > NROWS-1) g1 = NROWS-1;
            xs[rr0*132+cc] = hv[(size_t)g0*128 + cc] + a0[r];
            xs[rr1*132+cc] = hv[(size_t)g1*128 + cc] + a1[r];
        }
    }
    __syncthreads();

    // LN1: wave-parallel, 4 rows/wave, 64-lane butterfly
    {
        float g0 = ln1g[lane], g1 = ln1g[64+lane];
        float b0 = ln1b[lane], b1 = ln1b[64+lane];
#pragma unroll
        for (int i = 0; i < 4; i++) {
            int r = wave*4 + i;
            float x0 = xs[r*132 + lane], x1 = xs[r*132 + 64 + lane];
            float sm = x0 + x1, sq = x0*x0 + x1*x1;
#pragma unroll
            for (int m = 1; m < 64; m <<= 1) {
                sm += __shfl_xor(sm, m, 64);
                sq += __shfl_xor(sq, m, 64);
            }
            float mu = sm*(1.0f/H);
            float rs = rsqrtf(sq*(1.0f/H) - mu*mu + LN_EPS);
            float v0 = g0*(x0-mu)*rs + b0, v1 = g1*(x1-mu)*rs + b1;
            xs[r*132 + lane] = v0; xs[r*132 + 64 + lane] = v1;
            yz[r*136 + lane] = __float2bfloat16(v0);
            yz[r*136 + 64 + lane] = __float2bfloat16(v1);
        }
    }
    __syncthreads();

    // FF1: wave w -> n-tiles 4w..4w+3, frag reused across 2 m-tiles; t1 aliases Aus
    for (int ntl = 0; ntl < 4; ntl++) {
        int nt = wave*4 + ntl;
        int cc = nt*16 + lm;
        float b = bf1[cc];
        f4v a0 = {0.f,0.f,0.f,0.f}, a1 = a0;
#pragma unroll
        for (int ks = 0; ks < 4; ks++) {
            s8v wf = *(const s8v*)&Wf1_t[(size_t)(nt*16+lm)*128 + ks*32 + lq*8];
            s8v f0 = *(const s8v*)&yz[lm*136 + ks*32 + lq*8];
            s8v f1 = *(const s8v*)&yz[(16+lm)*136 + ks*32 + lq*8];
            a0 = __builtin_amdgcn_mfma_f32_16x16x32_bf16(f0, wf, a0, 0,0,0);
            a1 = __builtin_amdgcn_mfma_f32_16x16x32_bf16(f1, wf, a1, 0,0,0);
        }
#pragma unroll
        for (int r = 0; r < 4; r++) {
            t1[(lq*4+r)*520 + cc]      = __float2bfloat16(fmaxf(a0[r]+b, 0.f));
            t1[(16+lq*4+r)*520 + cc]   = __float2bfloat16(fmaxf(a1[r]+b, 0.f));
        }
    }
    __syncthreads();

    // FF2: wave w -> n-tile w, K=512
    {
        int cc = wave*16 + lm;
        float b = bf2[cc];
        f4v a0 = {0.f,0.f,0.f,0.f}, a1 = a0;
        for (int ks = 0; ks < 16; ks++) {
            s8v wf = *(const s8v*)&Wf2_t[(size_t)(wave*16+lm)*512 + ks*32 + lq*8];
            s8v f0 = *(const s8v*)&t1[lm*520 + ks*32 + lq*8];
            s8v f1 = *(const s8v*)&t1[(16+lm)*520 + ks*32 + lq*8];
            a0 = __builtin_amdgcn_mfma_f32_16x16x32_bf16(f0, wf, a0, 0,0,0);
            a1 = __builtin_amdgcn_mfma_f32_16x16x32_bf16(f1, wf, a1, 0,0,0);
        }
#pragma unroll
        for (int r = 0; r < 4; r++) {
            int rr0 = lq*4 + r, rr1 = 16 + lq*4 + r;
            xs[rr0*132+cc] = xs[rr0*132+cc] + a0[r] + b;
            xs[rr1*132+cc] = xs[rr1*132+cc] + a1[r] + b;
        }
    }
    __syncthreads();

    // LN2 + mask; write hv (guarded) + yz; final layer also computes out
    {
        float g0 = ln2g[lane], g1 = ln2g[64+lane];
        float b0 = ln2b[lane], b1 = ln2b[64+lane];
        float wo0 = 0.f, wo1 = 0.f, bo = 0.f;
        if (!Wn_t) { wo0 = W_out[lane]; wo1 = W_out[64+lane]; bo = b_out[0]; }
#pragma unroll
        for (int i = 0; i < 4; i++) {
            int r = wave*4 + i;
            int gr = row0 + r;
            float mk = mask[gr > NROWS-1 ? NROWS-1 : gr];
            float x0 = xs[r*132 + lane], x1 = xs[r*132 + 64 + lane];
            float sm = x0 + x1, sq = x0*x0 + x1*x1;
#pragma unroll
            for (int m = 1; m < 64; m <<= 1) {
                sm += __shfl_xor(sm, m, 64);
                sq += __shfl_xor(sq, m, 64);
            }
            float mu = sm*(1.0f/H);
            float rs = rsqrtf(sq*(1.0f/H) - mu*mu + LN_EPS);
            float v0 = mk*(g0*(x0-mu)*rs + b0), v1 = mk*(g1*(x1-mu)*rs + b1);
            yz[r*136 + lane] = __float2bfloat16(v0);
            yz[r*136 + 64 + lane] = __float2bfloat16(v1);
            if (gr < NROWS) {
                hv[(size_t)gr*128 + lane] = v0;
                hv[(size_t)gr*128 + 64 + lane] = v1;
            }
            if (!Wn_t) {
                float o = v0*wo0 + v1*wo1;
#pragma unroll
                for (int m = 1; m < 64; m <<= 1) o += __shfl_xor(o, m, 64);
                if (lane == 0 && gr < NROWS) out[gr] = o + bo;
            }
        }
    }
    __syncthreads();

    // next-layer node proj: 33 tiles over 8 waves (5 each, guard)
    if (Wn_t) {
        __hip_bfloat16* Pbw = (__hip_bfloat16*)P;
        for (int ntl = 0; ntl < 5; ntl++) {
            int nt = wave*5 + ntl;
            if (nt >= 33) break;
            int cc = nt*16 + lm;
            f4v a0 = {0.f,0.f,0.f,0.f}, a1 = a0;
#pragma unroll
            for (int ks = 0; ks < 4; ks++) {
                s8v wf = *(const s8v*)&Wn_t[(size_t)(nt*16+lm)*128 + ks*32 + lq*8];
                s8v f0 = *(const s8v*)&yz[lm*136 + ks*32 + lq*8];
                s8v f1 = *(const s8v*)&yz[(16+lm)*136 + ks*32 + lq*8];
                a0 = __builtin_amdgcn_mfma_f32_16x16x32_bf16(f0, wf, a0, 0,0,0);
                a1 = __builtin_amdgcn_mfma_f32_16x16x32_bf16(f1, wf, a1, 0,0,0);
            }
#pragma unroll
            for (int mt = 0; mt < 2; mt++) {
                f4v* ap = mt ? &a1 : &a0;
#pragma unroll
                for (int r = 0; r < 4; r++) {
                    int rr = row0 + mt*16 + lq*4 + r;
                    if (rr < NROWS) {
                        float av = (*ap)[r];
                        if (cc < 128)
                            P[(size_t)rr*P_F32_STRIDE + cc] = av;
                        else if (cc < 256)
                            Pbw[(size_t)rr*P_BF16_STRIDE + 640 + (cc-128)] = __float2bfloat16(av);
                        else if (cc < 272) {
                            if (cc < 260) qg_buf[rr*4 + (cc-256)] = av;
                        } else
                            PKV[(size_t)rr*256 + (cc-272)] = __float2bfloat16(av);
                    }
                }
            }
        }
    }
}

// ---------------------------------------------------------------- launch
extern "C" void kernel_launch(void* const* d_in, const int* in_sizes, int n_in,
                              void* d_out, int out_size, void* d_ws, size_t ws_size,
                              hipStream_t stream)
{
    const float* X      = (const float*)d_in[0];
    const float* V      = (const float*)d_in[1];
    const float* mask   = (const float*)d_in[2];
    const float* W_v    = (const float*)d_in[3];
    const float* b_v    = (const float*)d_in[4];
    const float* W_e    = (const float*)d_in[5];
    const float* b_e    = (const float*)d_in[6];
    const float* W_edge = (const float*)d_in[7];
    const float* ln_e_g = (const float*)d_in[8];
    const float* ln_e_b = (const float*)d_in[9];
    const float* Wq     = (const float*)d_in[10];
    const float* Wk     = (const float*)d_in[11];
    const float* Wv_a   = (const float*)d_in[12];
    const float* Wo     = (const float*)d_in[13];
    const float* ln1g   = (const float*)d_in[14];
    const float* ln1b   = (const float*)d_in[15];
    const float* ln2g   = (const float*)d_in[16];
    const float* ln2b   = (const float*)d_in[17];
    const float* Wf1    = (const float*)d_in[18];
    const float* bf1    = (const float*)d_in[19];
    const float* Wf2    = (const float*)d_in[20];
    const float* bf2    = (const float*)d_in[21];
    const float* W_out  = (const float*)d_in[22];
    const float* b_out  = (const float*)d_in[23];
    float* out = (float*)d_out;

    // workspace layout
    char* ws = (char*)d_ws;
    int*            E_idx    = (int*)ws;                                   //   720000
    float*          D_nb     = (float*)(ws + 720000);                      //   720000
    float*          hv       = (float*)(ws + 47520000);                    //  3072000
    float*          bias_kv  = (float*)(ws + 50592000);                    //     4096
    float*          Wkv_f    = (float*)(ws + 50596096);                    //   524288
    __hip_bfloat16* Wn_t     = (__hip_bfloat16*)(ws + 51120384);           //   540672 used
    __hip_bfloat16* WoU_t    = (__hip_bfloat16*)(ws + 52037888);           //   294912 used
    __hip_bfloat16* Wf1_t    = (__hip_bfloat16*)(ws + 52693248);           //   524288
    __hip_bfloat16* Wf2_t    = (__hip_bfloat16*)(ws + 53217536);           //   524288
    __hip_bfloat16* Wv_t     = (__hip_bfloat16*)(ws + 53741824);           //   262144
    __hip_bfloat16* W_edge_t = (__hip_bfloat16*)(ws + 54003968);           //     8192
    __hip_bfloat16* PKV      = (__hip_bfloat16*)(ws + 54012160);           //  3072000
    float*          P        = (float*)(ws + 57084160);                    //  9216000
    float*          EMS      = (float*)(ws + 66300160);                    //  1440000
    float*          M_buf    = (float*)(ws + 67740160);                    //    65536
    float*          vg_buf   = (float*)(ws + 67805696);                    //     2048
    float*          qg_buf   = (float*)(ws + 67807744);                    //    96000

    topk_kernel<<<NROWS, 256, 0, stream>>>(X, mask, E_idx, D_nb);
    wprep_cast_kernel<<<3856, 256, 0, stream>>>(
        W_edge, W_edge_t, W_v, Wv_t, Wf1, Wf2, Wq, Wk, Wv_a,
        Wf1_t, Wf2_t, Wn_t, W_e, b_e, Wkv_f, bias_kv);
    edge_kernel<<<NROWS/2, 256, 0, stream>>>(E_idx, D_nb, W_edge_t, EMS);
    wprep_mop_kernel<<<3168, 128, 0, stream>>>(
        Wkv_f, W_edge, ln_e_g, ln_e_b, Wo, M_buf, vg_buf, WoU_t);
    wprep_q2_kernel<<<512, 128, 0, stream>>>(Wq, M_buf, vg_buf, Wn_t);
    hv_init_kernel<<<(NROWS+31)/32, 512, 0, stream>>>(V, Wv_t, b_v, hv, Wn_t, P, PKV, qg_buf);

    for (int l = 0; l < 4; l++) {
        attn_kernel<<<NROWS/2, 256, 0, stream>>>(
            bias_kv + l*256 + 128, P, PKV, E_idx, D_nb, EMS, qg_buf, mask);
        post_kernel<<<(NROWS+31)/32, 512, 0, stream>>>(
            hv, P, PKV, qg_buf, mask, WoU_t + (size_t)l*128*UK,
            ln1g + l*H, ln1b + l*H, ln2g + l*H, ln2b + l*H,
            Wf1_t + (size_t)l*65536, bf1 + l*FFH,
            Wf2_t + (size_t)l*65536, bf2 + l*H,
            (l < 3) ? (Wn_t + (size_t)(l+1)*WNT_STRIDE) : (const __hip_bfloat16*)nullptr,
            W_out, b_out, out);
    }
}